// Round 10
// baseline (303.012 us; speedup 1.0000x reference)
//
#include <hip/hip_runtime.h>
#include <hip/hip_bf16.h>
#include <math.h>
#include <stdint.h>

typedef __bf16 bf16_t;
typedef __bf16 bf16x4 __attribute__((ext_vector_type(4)));
typedef __bf16 bf16x8 __attribute__((ext_vector_type(8)));
typedef float floatx4 __attribute__((ext_vector_type(4)));

#define BM 128
#define BK 32

// fragment-tiled address: 16-row x 32-k tiles, chunk-major inside
__device__ __forceinline__ size_t ftaddr(int m, int k, int KT) {
    return ((size_t)(m >> 4) * KT + (k >> 5)) * 512
         + (((k >> 3) & 3) * 16 + (m & 15)) * 8 + (k & 7);
}

__device__ __forceinline__ void gload16(const void* g, void* lds) {
    __builtin_amdgcn_global_load_lds(
        (__attribute__((address_space(1))) void*)(uintptr_t)g,
        (__attribute__((address_space(3))) void*)(uintptr_t)lds,
        16, 0, 0);
}

// compile-time vmcnt wait + barrier
template<int N>
__device__ __forceinline__ void waitvm_barrier() {
    if constexpr (N == 0)       asm volatile("s_waitcnt vmcnt(0)\n\ts_barrier" ::: "memory");
    else if constexpr (N == 4)  asm volatile("s_waitcnt vmcnt(4)\n\ts_barrier" ::: "memory");
    else if constexpr (N == 6)  asm volatile("s_waitcnt vmcnt(6)\n\ts_barrier" ::: "memory");
    else if constexpr (N == 8)  asm volatile("s_waitcnt vmcnt(8)\n\ts_barrier" ::: "memory");
    else if constexpr (N == 12) asm volatile("s_waitcnt vmcnt(12)\n\ts_barrier" ::: "memory");
    else if constexpr (N == 16) asm volatile("s_waitcnt vmcnt(16)\n\ts_barrier" ::: "memory");
    else static_assert(N == 0, "unsupported vmcnt");
}

// runtime (wave-uniform) vmcnt wait + barrier for the drain tail
__device__ __forceinline__ void waitvm_barrier_rt(int n) {
    switch (n) {
    case 12: asm volatile("s_waitcnt vmcnt(12)\n\ts_barrier" ::: "memory"); break;
    case 8:  asm volatile("s_waitcnt vmcnt(8)\n\ts_barrier"  ::: "memory"); break;
    case 6:  asm volatile("s_waitcnt vmcnt(6)\n\ts_barrier"  ::: "memory"); break;
    case 4:  asm volatile("s_waitcnt vmcnt(4)\n\ts_barrier"  ::: "memory"); break;
    default: asm volatile("s_waitcnt vmcnt(0)\n\ts_barrier"  ::: "memory"); break;
    }
}

// ---------------- prep: weight transposes (blocks 0..3071) + ln1 (3072..3327)
__global__ void prep_kernel(const float* __restrict__ wq, const float* __restrict__ wk,
                            const float* __restrict__ wv, const float* __restrict__ w_proj,
                            const float* __restrict__ w1, const float* __restrict__ w2,
                            bf16_t* __restrict__ WQKVT, bf16_t* __restrict__ WPROJT,
                            bf16_t* __restrict__ W1T, bf16_t* __restrict__ W2T,
                            const float* __restrict__ x, const float* __restrict__ g1,
                            const float* __restrict__ be1, bf16_t* __restrict__ HB)
{
    __shared__ __align__(16) char psm[33024];
    const int tid = threadIdx.x;
    if (blockIdx.x < 3072) {
        // ---- weight transpose + cast, fragment-tiled coalesced writes ----
        float (*tile)[65] = (float(*)[65])psm;
        const int idx = blockIdx.x;
        const float* in; bf16_t* out; int R, C, rt, ct; long nrow0;
        if (idx < 768) {
            const int z = idx >> 8;
            const int hd = (idx >> 4) & 15;
            rt = idx & 15; ct = 0; R = 1024; C = 64;
            in  = (z == 0 ? wq : z == 1 ? wk : wv) + hd * 65536;
            out = WQKVT; nrow0 = z * 1024 + hd * 64;
        } else if (idx < 1024) {
            const int t = idx - 768; rt = t & 15; ct = t >> 4; R = 1024; C = 1024;
            in = w_proj; out = WPROJT; nrow0 = 0;
        } else if (idx < 2048) {
            const int t = idx - 1024; rt = t & 15; ct = t >> 4; R = 1024; C = 4096;
            in = w1; out = W1T; nrow0 = 0;
        } else {
            const int t = idx - 2048; rt = t & 63; ct = t >> 6; R = 4096; C = 1024;
            in = w2; out = W2T; nrow0 = 0;
        }
        const int r0 = rt * 64, c0 = ct * 64;
        const int tr = tid >> 4;
        const int tc = (tid & 15) * 4;
#pragma unroll
        for (int rr = 0; rr < 4; rr++) {
            const int r = tr + rr * 16;
            const float4 v = *(const float4*)&in[(long)(r0 + r) * C + c0 + tc];
            tile[r][tc + 0] = v.x; tile[r][tc + 1] = v.y;
            tile[r][tc + 2] = v.z; tile[r][tc + 3] = v.w;
        }
        __syncthreads();
        const int KT = R >> 5;
        const int w = tid >> 6, l = tid & 63;
        const int c = l >> 4, rr2 = l & 15;
#pragma unroll
        for (int it = 0; it < 2; ++it) {
            const int t8 = it * 4 + w;
            const int kt = t8 >> 2;
            const int nb = t8 & 3;
            const long n = nrow0 + c0 + nb * 16 + rr2;
            const int k = r0 + kt * 32 + c * 8;
            bf16x8 o;
#pragma unroll
            for (int e = 0; e < 8; e++)
                o[e] = (bf16_t)tile[kt * 32 + c * 8 + e][nb * 16 + rr2];
            *(bf16x8*)&out[ftaddr((int)n, k, KT)] = o;
        }
    } else {
        // ---- layernorm, 16 rows/block, tiled-coalesced bf16 out ----
        bf16_t (*ybuf)[1032] = (bf16_t(*)[1032])psm;
        const int wave = tid >> 6, lane = tid & 63;
        const int rb = blockIdx.x - 3072;
        float4 gvv[4], bvv[4];
#pragma unroll
        for (int j = 0; j < 4; j++) {
            gvv[j] = ((const float4*)g1)[lane + j * 64];
            bvv[j] = ((const float4*)be1)[lane + j * 64];
        }
#pragma unroll
        for (int rr = 0; rr < 4; ++rr) {
            const int lrow = wave * 4 + rr;
            const float* xr = x + (size_t)(rb * 16 + lrow) * 1024;
            float4 v[4];
            float s = 0.f, s2 = 0.f;
#pragma unroll
            for (int j = 0; j < 4; j++) {
                v[j] = ((const float4*)xr)[lane + j * 64];
                s  += v[j].x + v[j].y + v[j].z + v[j].w;
                s2 += v[j].x * v[j].x + v[j].y * v[j].y + v[j].z * v[j].z + v[j].w * v[j].w;
            }
#pragma unroll
            for (int off = 32; off >= 1; off >>= 1) {
                s  += __shfl_xor(s, off);
                s2 += __shfl_xor(s2, off);
            }
            const float mu = s * (1.0f / 1024.0f);
            const float rs = rsqrtf(fmaxf(s2 * (1.0f / 1024.0f) - mu * mu, 0.f) + 1e-5f);
#pragma unroll
            for (int j = 0; j < 4; j++) {
                bf16x4 o;
                o[0] = (bf16_t)((v[j].x - mu) * rs * gvv[j].x + bvv[j].x);
                o[1] = (bf16_t)((v[j].y - mu) * rs * gvv[j].y + bvv[j].y);
                o[2] = (bf16_t)((v[j].z - mu) * rs * gvv[j].z + bvv[j].z);
                o[3] = (bf16_t)((v[j].w - mu) * rs * gvv[j].w + bvv[j].w);
                *(bf16x4*)&ybuf[lrow][(lane + j * 64) * 4] = o;
            }
        }
        __syncthreads();
        bf16_t* outBase = HB + (size_t)rb * 32 * 512;
#pragma unroll
        for (int it = 0; it < 8; ++it) {
            const int s = it * 256 + tid;
            const int kt = s >> 6, c = (s >> 4) & 3, rr2 = s & 15;
            const bf16x8 val = *(const bf16x8*)&ybuf[rr2][kt * 32 + c * 8];
            *(bf16x8*)&outBase[(size_t)s * 8] = val;
        }
    }
}

// ---------------- double layernorm: ln(ln(x)), tiled-coalesced out ------
__global__ void ln2x_kernel(const float* __restrict__ x, const float* __restrict__ g,
                            const float* __restrict__ b, bf16_t* __restrict__ outb)
{
    __shared__ __align__(16) bf16_t ybuf[16][1032];
    const int tid = threadIdx.x, wave = tid >> 6, lane = tid & 63;
    const int rb = blockIdx.x;
    float4 gvv[4], bvv[4];
#pragma unroll
    for (int j = 0; j < 4; j++) {
        gvv[j] = ((const float4*)g)[lane + j * 64];
        bvv[j] = ((const float4*)b)[lane + j * 64];
    }
#pragma unroll
    for (int rr = 0; rr < 4; ++rr) {
        const int lrow = wave * 4 + rr;
        const float* xr = x + (size_t)(rb * 16 + lrow) * 1024;
        float4 v[4];
        float s = 0.f, s2 = 0.f;
#pragma unroll
        for (int j = 0; j < 4; j++) {
            v[j] = ((const float4*)xr)[lane + j * 64];
            s  += v[j].x + v[j].y + v[j].z + v[j].w;
            s2 += v[j].x * v[j].x + v[j].y * v[j].y + v[j].z * v[j].z + v[j].w * v[j].w;
        }
#pragma unroll
        for (int off = 32; off >= 1; off >>= 1) {
            s  += __shfl_xor(s, off);
            s2 += __shfl_xor(s2, off);
        }
        float mu = s * (1.0f / 1024.0f);
        float rs = rsqrtf(fmaxf(s2 * (1.0f / 1024.0f) - mu * mu, 0.f) + 1e-5f);
        s = 0.f; s2 = 0.f;
#pragma unroll
        for (int j = 0; j < 4; j++) {
            v[j].x = (v[j].x - mu) * rs * gvv[j].x + bvv[j].x;
            v[j].y = (v[j].y - mu) * rs * gvv[j].y + bvv[j].y;
            v[j].z = (v[j].z - mu) * rs * gvv[j].z + bvv[j].z;
            v[j].w = (v[j].w - mu) * rs * gvv[j].w + bvv[j].w;
            s  += v[j].x + v[j].y + v[j].z + v[j].w;
            s2 += v[j].x * v[j].x + v[j].y * v[j].y + v[j].z * v[j].z + v[j].w * v[j].w;
        }
#pragma unroll
        for (int off = 32; off >= 1; off >>= 1) {
            s  += __shfl_xor(s, off);
            s2 += __shfl_xor(s2, off);
        }
        mu = s * (1.0f / 1024.0f);
        rs = rsqrtf(fmaxf(s2 * (1.0f / 1024.0f) - mu * mu, 0.f) + 1e-5f);
#pragma unroll
        for (int j = 0; j < 4; j++) {
            bf16x4 o;
            o[0] = (bf16_t)((v[j].x - mu) * rs * gvv[j].x + bvv[j].x);
            o[1] = (bf16_t)((v[j].y - mu) * rs * gvv[j].y + bvv[j].y);
            o[2] = (bf16_t)((v[j].z - mu) * rs * gvv[j].z + bvv[j].z);
            o[3] = (bf16_t)((v[j].w - mu) * rs * gvv[j].w + bvv[j].w);
            *(bf16x4*)&ybuf[lrow][(lane + j * 64) * 4] = o;
        }
    }
    __syncthreads();
    bf16_t* outBase = outb + (size_t)rb * 32 * 512;
#pragma unroll
    for (int it = 0; it < 8; ++it) {
        const int s = it * 256 + tid;
        const int kt = s >> 6, c = (s >> 4) & 3, rr2 = s & 15;
        const bf16x8 val = *(const bf16x8*)&ybuf[rr2][kt * 32 + c * 8];
        *(bf16x8*)&outBase[(size_t)s * 8] = val;
    }
}

// ---------------- reg-A GEMM (proj, FF1, FF2): 128x64 tile, B-only LDS ---
// R10: A prefetched TWO half-iters (8 steps) ahead into R[8][2]
// (compile-time indexed — rule #20), B staged 8 steps ahead in a 12-buffer
// ring. Ledger: 12 VMEM ops per 4-step half ([B,A,A]x4); a single
// vmcnt(12)+barrier per half proves ALL ops >=2 halves old landed (both
// B-stages and A-reg loads) -> no per-slot waits (R9's vmcnt(10) +
// sched_barrier per step was the serialization limiter). A-load slack
// ~2 half-iters ~ 1500cy > HBM miss latency.
// EPI=1/3: fp32 out + bias + resid. EPI=2: relu + bf16 tiled (ftaddr).
template<int EPI>
__global__ __launch_bounds__(256, 2)
void gemm_ra(const bf16_t* __restrict__ A, const bf16_t* __restrict__ Bt,
             const int K, const float* __restrict__ bias,
             const float* __restrict__ resid, float* __restrict__ outf,
             bf16_t* __restrict__ outb, const int Nout)
{
    constexpr int D = 12;
    __shared__ __align__(16) bf16_t Bs[D * 2048];   // 48 KB
    const int tid = threadIdx.x, wave = tid >> 6, lane = tid & 63;
    const int bm = blockIdx.x * BM, bn = blockIdx.y * 64;
    const int KT = K >> 5;
    const int NT = K >> 5;          // 32 (proj/FF1) or 128 (FF2); mult of 8
    const int NTm = NT - 1;

    floatx4 acc[2][4];
#pragma unroll
    for (int i = 0; i < 2; i++)
#pragma unroll
        for (int j = 0; j < 4; j++) acc[i][j] = (floatx4){0.f, 0.f, 0.f, 0.f};

    const bf16_t* gA0 = A + ((size_t)(bm / 16 + wave * 2 + 0) * KT) * 512 + lane * 8;
    const bf16_t* gA1 = A + ((size_t)(bm / 16 + wave * 2 + 1) * KT) * 512 + lane * 8;
    const bf16_t* gB  = Bt + ((size_t)(bn / 16 + wave) * KT) * 512 + lane * 8;

    auto stageB = [&](int t, int b) {
        gload16(gB + (size_t)t * 512, Bs + b * 2048 + wave * 512);
    };
    auto loadA = [&](bf16x8& r0, bf16x8& r1, int t) {
        const bf16_t* p0 = gA0 + (size_t)t * 512;
        const bf16_t* p1 = gA1 + (size_t)t * 512;
        asm volatile("global_load_dwordx4 %0, %1, off"
                     : "=&v"(r0) : "v"(p0) : "memory");
        asm volatile("global_load_dwordx4 %0, %1, off"
                     : "=&v"(r1) : "v"(p1) : "memory");
    };
    auto computeS = [&](const bf16x8& a0, const bf16x8& a1, int b) {
        bf16x8 bfv[4];
#pragma unroll
        for (int j = 0; j < 4; j++)
            bfv[j] = *(const bf16x8*)&Bs[b * 2048 + j * 512 + lane * 8];
#pragma unroll
        for (int j = 0; j < 4; j++) {
            acc[0][j] = __builtin_amdgcn_mfma_f32_16x16x32_bf16(a0, bfv[j], acc[0][j], 0, 0, 0);
            acc[1][j] = __builtin_amdgcn_mfma_f32_16x16x32_bf16(a1, bfv[j], acc[1][j], 0, 0, 0);
        }
    };

    bf16x8 R[8][2];
    // prologue: two pseudo-halves, each 12 VMEM ops in [B,A,A]x4 order
#pragma unroll
    for (int i = 0; i < 4; i++) {
        stageB(i, i);
        loadA(R[i][0], R[i][1], i);
    }
#pragma unroll
    for (int i = 0; i < 4; i++) {
        stageB(4 + i, 4 + i);
        loadA(R[4 + i][0], R[4 + i][1], 4 + i);
    }

    int bu = 0;                       // B buffer of step t
    const int NU = NT >> 3;           // 8 steps per outer iter
    for (int U = 0; U < NU; U++) {
        const int t = U << 3;
#pragma unroll
        for (int hf = 0; hf < 2; hf++) {
            const int th = t + hf * 4;
            asm volatile("s_waitcnt vmcnt(12)\n\ts_barrier" ::: "memory");
            __builtin_amdgcn_sched_barrier(0);
#pragma unroll
            for (int i = 0; i < 4; i++) {
                int bs = bu + 8 + i; if (bs >= D) bs -= D;
                stageB((th + 8 + i) & NTm, bs);
                int bc = bu + i; if (bc >= D) bc -= D;
                computeS(R[hf * 4 + i][0], R[hf * 4 + i][1], bc);
                loadA(R[hf * 4 + i][0], R[hf * 4 + i][1], (th + 8 + i) & NTm);
            }
            bu += 4; if (bu >= D) bu -= D;
        }
    }
    asm volatile("s_waitcnt vmcnt(0)" ::: "memory");

    const int er = (lane >> 4) * 4, ec = lane & 15;
#pragma unroll
    for (int i = 0; i < 2; i++) {
#pragma unroll
        for (int j = 0; j < 4; j++) {
            const int col = bn + j * 16 + ec;
#pragma unroll
            for (int r = 0; r < 4; r++) {
                const int row = bm + wave * 32 + i * 16 + er + r;
                const float v = acc[i][j][r];
                if (EPI == 2) {
                    outb[ftaddr(row, col, Nout >> 5)] = (bf16_t)fmaxf(v + bias[col], 0.f);
                } else {
                    const size_t idx = (size_t)row * Nout + col;
                    outf[idx] = v + bias[col] + resid[idx];
                }
            }
        }
    }
}

// ---------------- bf16 MFMA GEMM (QKV): 128x128, 2x2 waves, DEPTH=5 ------
template<int EPI, int BNt, int DEPTH>
__global__ __launch_bounds__(256, 2)
void gemm_bt(const bf16_t* __restrict__ A, const bf16_t* __restrict__ Bt,
             const int K,
             const float* __restrict__ bias, const float* __restrict__ resid,
             float* __restrict__ outf, bf16_t* __restrict__ outb,
             bf16_t* __restrict__ aux1, bf16_t* __restrict__ aux2,
             const int Nout)
{
    constexpr int NFRAG = (BNt == 256) ? 8 : 4;    // B-frags per wave
    constexpr int AI    = 4;                       // A-frags per wave
    constexpr int LPS   = (BNt == 256) ? 6 : 4;
    constexpr int BFT   = BNt / 16;                // B ftiles per stage
    constexpr int ASZ = DEPTH * 8 * 512;
    constexpr int BSZ = DEPTH * BFT * 512;
    __shared__ __align__(16) bf16_t smem[ASZ + BSZ];
    bf16_t* Asb = smem;
    bf16_t* Bsb = smem + ASZ;
    const int tid  = threadIdx.x;
    const int wave = tid >> 6, lane = tid & 63;
    const int wr = wave >> 1, wc = wave & 1;  // 2x2 wave grid
    const int bm = blockIdx.x * BM, bn = blockIdx.y * BNt;
    const int KT = K >> 5;

    floatx4 acc[AI][NFRAG];
#pragma unroll
    for (int i = 0; i < AI; i++)
#pragma unroll
        for (int j = 0; j < NFRAG; j++) acc[i][j] = (floatx4){0.f, 0.f, 0.f, 0.f};

    const bf16_t* gA0 = A + ((size_t)(bm / 16 + wave * 2 + 0) * KT) * 512 + lane * 8;
    const bf16_t* gA1 = A + ((size_t)(bm / 16 + wave * 2 + 1) * KT) * 512 + lane * 8;
    const int lA0 = (wave * 2 + 0) * 512;
    const int lA1 = (wave * 2 + 1) * 512;

    const bf16_t* gB[4];
    if (BNt == 256) {
#pragma unroll
        for (int q = 0; q < 4; q++)
            gB[q] = Bt + ((size_t)(bn / 16 + wave * 4 + q) * KT) * 512 + lane * 8;
    } else {
        gB[0] = Bt + ((size_t)(bn / 16 + wave * 2 + 0) * KT) * 512 + lane * 8;
        gB[1] = Bt + ((size_t)(bn / 16 + wave * 2 + 1) * KT) * 512 + lane * 8;
    }

    auto stage = [&](int t, int bu) {
        const size_t off = (size_t)t * 512;
        gload16(gA0 + off, Asb + bu * 4096 + lA0);
        gload16(gA1 + off, Asb + bu * 4096 + lA1);
        if (BNt == 256) {
#pragma unroll
            for (int q = 0; q < 4; q++)
                gload16(gB[q] + off, Bsb + bu * (BFT * 512) + (wave * 4 + q) * 512);
        } else {
            gload16(gB[0] + off, Bsb + bu * 4096 + lA0);
            gload16(gB[1] + off, Bsb + bu * 4096 + lA1);
        }
    };

    auto compute = [&](int bu) {
        bf16x8 af[AI], bfv[NFRAG];
#pragma unroll
        for (int i = 0; i < AI; i++)
            af[i] = *(const bf16x8*)&Asb[bu * 4096 + (wr * 4 + i) * 512 + lane * 8];
#pragma unroll
        for (int j = 0; j < NFRAG; j++)
            bfv[j] = *(const bf16x8*)&Bsb[bu * (BFT * 512) + (wc * NFRAG + j) * 512 + lane * 8];
#pragma unroll
        for (int i = 0; i < AI; i++)
#pragma unroll
            for (int j = 0; j < NFRAG; j++)
                acc[i][j] = __builtin_amdgcn_mfma_f32_16x16x32_bf16(af[i], bfv[j], acc[i][j], 0, 0, 0);
    };

    const int NT = K / BK;
    // ---- every-iter barrier pipeline ----
#pragma unroll
    for (int i = 0; i < DEPTH - 1; ++i) stage(i, i);
    int bu = 0;
    for (int t = 0; t <= NT - DEPTH; ++t) {
        waitvm_barrier<LPS * (DEPTH - 2)>();
        stage(t + DEPTH - 1, bu == 0 ? DEPTH - 1 : bu - 1);
        compute(bu);
        bu = (bu + 1 == DEPTH) ? 0 : bu + 1;
    }
#pragma unroll
    for (int j = DEPTH - 2; j >= 0; --j) {
        waitvm_barrier_rt(LPS * j);
        compute(bu);
        bu = (bu + 1 == DEPTH) ? 0 : bu + 1;
    }

    const int er = (lane >> 4) * 4, ec = lane & 15;
    if constexpr (EPI == 0) {
        if (bn >= 2048) {
            // V-block: LDS transpose then coalesced [d][t] writes
            __syncthreads();                      // staging LDS now dead
            bf16_t* scr = smem;                   // 128 x 136 (pad) bf16 = 34 KB
#pragma unroll
            for (int i = 0; i < AI; i++)
#pragma unroll
                for (int j = 0; j < NFRAG; j++)
#pragma unroll
                    for (int r = 0; r < 4; r++)
                        scr[((wc * NFRAG + j) * 16 + ec) * 136 + (wr * 4 + i) * 16 + er + r] =
                            (bf16_t)acc[i][j][r];
            __syncthreads();
            const int bq = bm >> 10, tmod = bm & 1023, h0 = (bn - 2048) >> 6;
#pragma unroll
            for (int it = 0; it < 8; ++it) {
                const int c = it * 256 + tid;
                const int dl = c >> 4, t16 = c & 15;
                const bf16x8 val = *(const bf16x8*)&scr[dl * 136 + t16 * 8];
                const int h = h0 + (dl >> 6), dd = dl & 63;
                *(bf16x8*)&aux2[(size_t)((bq * 16 + h) * 64 + dd) * 1024 + tmod + t16 * 8] = val;
            }
            return;
        }
    }
#pragma unroll
    for (int i = 0; i < AI; i++) {
#pragma unroll
        for (int j = 0; j < NFRAG; j++) {
            const int col = bn + (wc * NFRAG + j) * 16 + ec;
#pragma unroll
            for (int r = 0; r < 4; r++) {
                const int row = bm + (wr * 4 + i) * 16 + er + r;
                const float v = acc[i][j][r];
                if (EPI == 0) {
                    const int b = row >> 10, t = row & 1023;
                    if (col < 1024) {
                        const int h = col >> 6, d = col & 63;
                        outb[(size_t)((b * 16 + h) * 1024 + t) * 64 + d] = (bf16_t)v;
                    } else {
                        const int c2 = col - 1024, h = c2 >> 6, d = c2 & 63;
                        aux1[(size_t)((b * 16 + h) * 1024 + t) * 64 + d] = (bf16_t)v;
                    }
                } else if (EPI == 2) {
                    outb[ftaddr(row, col, Nout >> 5)] = (bf16_t)fmaxf(v + bias[col], 0.f);
                }
            }
        }
    }
}

// ---------------- flash attention (R9-verified: coalesced swizzled staging)
__global__ __launch_bounds__(256, 4)
void attn_kernel(const bf16_t* __restrict__ Q, const bf16_t* __restrict__ Kg,
                 const bf16_t* __restrict__ Vt, bf16_t* __restrict__ Og)
{
    __shared__ __align__(16) bf16_t Ks[2][4096];
    __shared__ __align__(16) bf16_t Vs[2][4096];
    __shared__ __align__(16) bf16_t Ps[4][1024];
    const int tid = threadIdx.x, wave = tid >> 6, lane = tid & 63;
    const int lin = blockIdx.x + (blockIdx.y << 4);
    const int xcd = lin & 7, idx = lin >> 3;
    const int bh = xcd * 8 + (idx >> 4);
    const int qt = idx & 15;
    const int b = bh >> 4, h = bh & 15;
    const int q0 = qt * 64 + wave * 16;
    const bf16_t* Qb = Q + (size_t)bh * 65536;
    const char* Kb = (const char*)(Kg + (size_t)bh * 65536);
    const char* Vb = (const char*)(Vt + (size_t)bh * 65536);
    const int fr = lane & 15, g = lane >> 4, fk = g * 8;

    const bf16x8 qf0 = *(const bf16x8*)&Qb[(size_t)(q0 + fr) * 64 + fk];
    const bf16x8 qf1 = *(const bf16x8*)&Qb[(size_t)(q0 + fr) * 64 + 32 + fk];

    floatx4 o[4];
#pragma unroll
    for (int dt = 0; dt < 4; dt++) o[dt] = (floatx4){0.f, 0.f, 0.f, 0.f};
    float lsum[4] = {0.f, 0.f, 0.f, 0.f};
    bf16_t* pw = &Ps[wave][0];
    const float sscale = 0.125f * 1.44269504088896f;

    const int sub = lane >> 3;               // row within 8-row group
    const int cc  = (lane & 7) ^ sub;        // swizzled 16B chunk (involution)
    auto stage = [&](int s0, int bu) {
#pragma unroll
        for (int t = 0; t < 2; t++) {
            const int j = wave * 2 + t;      // 8-row slot 0..7
            const int row = j * 8 + sub;     // 0..63
            gload16(Kb + (size_t)(s0 + row) * 128 + cc * 16, &Ks[bu][j * 512]);
            gload16(Vb + (size_t)row * 2048 + (size_t)s0 * 2 + cc * 16, &Vs[bu][j * 512]);
        }
    };

    stage(0, 0);
    int bu = 0;
    for (int it = 0; it < 16; ++it) {
        __syncthreads();
        if (it < 15) stage((it + 1) * 64, bu ^ 1);
        const bf16_t* Kl = Ks[bu];
        const bf16_t* Vl = Vs[bu];

        floatx4 sacc[4];
#pragma unroll
        for (int ss = 0; ss < 4; ss++) sacc[ss] = (floatx4){0.f, 0.f, 0.f, 0.f};
        __builtin_amdgcn_s_setprio(1);
#pragma unroll
        for (int ss = 0; ss < 4; ss++) {
#pragma unroll
            for (int c = 0; c < 2; c++) {
                const int ch = c * 4 + g;
                const bf16x8 qf = (c == 0) ? qf0 : qf1;
                const bf16x8 kf = *(const bf16x8*)
                    &Kl[(ss * 16 + fr) * 64 + ((ch ^ (fr & 7)) << 3)];
                sacc[ss] = __builtin_amdgcn_mfma_f32_16x16x32_bf16(qf, kf, sacc[ss], 0, 0, 0);
            }
        }
        __builtin_amdgcn_s_setprio(0);
#pragma unroll
        for (int ss = 0; ss < 2; ss++) {
#pragma unroll
            for (int r = 0; r < 4; r++) {
                const float p = __builtin_amdgcn_exp2f(sacc[ss][r] * sscale);
                lsum[r] += p;
                const int q = g * 4 + r;
                pw[(ss * 2 + (fr >> 3)) * 128 + q * 8 + (fr & 7)] = (bf16_t)p;
            }
        }
        asm volatile("s_waitcnt lgkmcnt(0)" ::: "memory");
#pragma unroll
        for (int ss = 2; ss < 4; ss++) {
#pragma unroll
            for (int r = 0; r < 4; r++) {
                const float p = __builtin_amdgcn_exp2f(sacc[ss][r] * sscale);
                lsum[r] += p;
                const int q = g * 4 + r;
                pw[(ss * 2 + (fr >> 3)) * 128 + q * 8 + (fr & 7)] = (bf16_t)p;
            }
        }
        {
            const int ch = g;
            const bf16x8 pf = *(const bf16x8*)&pw[ch * 128 + fr * 8];
            __builtin_amdgcn_s_setprio(1);
#pragma unroll
            for (int dt = 0; dt < 4; dt++) {
                const bf16x8 vf = *(const bf16x8*)
                    &Vl[(dt * 16 + fr) * 64 + ((ch ^ (fr & 7)) << 3)];
                o[dt] = __builtin_amdgcn_mfma_f32_16x16x32_bf16(pf, vf, o[dt], 0, 0, 0);
            }
            __builtin_amdgcn_s_setprio(0);
        }
        asm volatile("s_waitcnt lgkmcnt(0)" ::: "memory");
        {
            const int ch = 4 + g;
            const bf16x8 pf = *(const bf16x8*)&pw[ch * 128 + fr * 8];
            __builtin_amdgcn_s_setprio(1);
#pragma unroll
            for (int dt = 0; dt < 4; dt++) {
                const bf16x8 vf = *(const bf16x8*)
                    &Vl[(dt * 16 + fr) * 64 + ((ch ^ (fr & 7)) << 3)];
                o[dt] = __builtin_amdgcn_mfma_f32_16x16x32_bf16(pf, vf, o[dt], 0, 0, 0);
            }
            __builtin_amdgcn_s_setprio(0);
        }
        asm volatile("" ::: "memory");
        bu ^= 1;
    }
#pragma unroll
    for (int r = 0; r < 4; r++) {
        float l = lsum[r];
        l += __shfl_xor(l, 1);
        l += __shfl_xor(l, 2);
        l += __shfl_xor(l, 4);
        l += __shfl_xor(l, 8);
        lsum[r] = 1.0f / l;
    }
    const int tq = q0 + g * 4;
#pragma unroll
    for (int dt = 0; dt < 4; dt++) {
#pragma unroll
        for (int r = 0; r < 4; r++) {
            const int m = b * 1024 + tq + r;
            const int k = h * 64 + dt * 16 + fr;
            Og[ftaddr(m, k, 32)] = (bf16_t)(o[dt][r] * lsum[r]);
        }
    }
}

// -------------------------------------------------------------------------
extern "C" void kernel_launch(void* const* d_in, const int* in_sizes, int n_in,
                              void* d_out, int out_size, void* d_ws, size_t ws_size,
                              hipStream_t stream)
{
    const float* x      = (const float*)d_in[0];
    const float* wq     = (const float*)d_in[1];
    const float* wk     = (const float*)d_in[2];
    const float* wv     = (const float*)d_in[3];
    const float* w_proj = (const float*)d_in[4];
    const float* b_proj = (const float*)d_in[5];
    const float* w1     = (const float*)d_in[6];
    const float* b1     = (const float*)d_in[7];
    const float* w2     = (const float*)d_in[8];
    const float* b2     = (const float*)d_in[9];
    const float* g1     = (const float*)d_in[10];
    const float* be1    = (const float*)d_in[11];
    const float* g2     = (const float*)d_in[12];
    const float* be2    = (const float*)d_in[13];
    float* out = (float*)d_out;
    char* ws = (char*)d_ws;

    bf16_t* WQKVT = (bf16_t*)(ws + 0x0000000);  // [3072,1024] tiled, 6 MB
    bf16_t* WPROJT= (bf16_t*)(ws + 0x0600000);  // [1024,1024] tiled, 2 MB
    bf16_t* W1T   = (bf16_t*)(ws + 0x0800000);  // [4096,1024] tiled, 8 MB
    bf16_t* W2T   = (bf16_t*)(ws + 0x1000000);  // [1024,4096] tiled, 8 MB
    bf16_t* HB    = (bf16_t*)(ws + 0x1800000);  // ln1 out tiled, 8 MB
    bf16_t* Qb    = (bf16_t*)(ws + 0x2000000);  // [BH,T,64] bf16, 8 MB
    bf16_t* Kb    = (bf16_t*)(ws + 0x2800000);  // [BH,T,64] bf16, 8 MB
    bf16_t* Vtb   = (bf16_t*)(ws + 0x3000000);  // [BH,64,T] bf16, 8 MB
    bf16_t* AO    = (bf16_t*)(ws + 0x3800000);  // attn out tiled, 8 MB
    float*  X2    = (float*)(ws + 0x4000000);   // x+sa fp32 row-major, 16 MB
    bf16_t* TB    = (bf16_t*)(ws + 0x2800000);  // ln2(ln2) tiled (reuses Kb), 8 MB
    bf16_t* FF1B  = (bf16_t*)(ws + 0x5000000);  // [4096,4096] tiled, 32 MB

    dim3 blk(256);
    prep_kernel<<<3328, blk, 0, stream>>>(wq, wk, wv, w_proj, w1, w2,
                                          WQKVT, WPROJT, W1T, W2T,
                                          x, g1, be1, HB);
    gemm_bt<0, 128, 5><<<dim3(32, 24), blk, 0, stream>>>(HB, WQKVT, 1024, nullptr, nullptr,
                                                         nullptr, Qb, Kb, Vtb, 3072);
    attn_kernel<<<dim3(16, 64), blk, 0, stream>>>(Qb, Kb, Vtb, AO);
    // proj: reg-A GEMM
    gemm_ra<1><<<dim3(32, 16), blk, 0, stream>>>(AO, WPROJT, 1024, b_proj, x, X2,
                                                 nullptr, 1024);
    ln2x_kernel<<<256, blk, 0, stream>>>(X2, g2, be2, TB);
    // FF1: reg-A GEMM, relu + tiled bf16 out
    gemm_ra<2><<<dim3(32, 64), blk, 0, stream>>>(TB, W1T, 1024, b1, nullptr, nullptr,
                                                 FF1B, 4096);
    // FF2: reg-A GEMM
    gemm_ra<3><<<dim3(32, 16), blk, 0, stream>>>(FF1B, W2T, 4096, b2, X2, out,
                                                 nullptr, 1024);
}

// Round 11
// 295.378 us; speedup vs baseline: 1.0258x; 1.0258x over previous
//
#include <hip/hip_runtime.h>
#include <hip/hip_bf16.h>
#include <math.h>
#include <stdint.h>

typedef __bf16 bf16_t;
typedef __bf16 bf16x4 __attribute__((ext_vector_type(4)));
typedef __bf16 bf16x8 __attribute__((ext_vector_type(8)));
typedef float floatx4 __attribute__((ext_vector_type(4)));

#define BM 128
#define BK 32

// fragment-tiled address: 16-row x 32-k tiles, chunk-major inside
__device__ __forceinline__ size_t ftaddr(int m, int k, int KT) {
    return ((size_t)(m >> 4) * KT + (k >> 5)) * 512
         + (((k >> 3) & 3) * 16 + (m & 15)) * 8 + (k & 7);
}

__device__ __forceinline__ void gload16(const void* g, void* lds) {
    __builtin_amdgcn_global_load_lds(
        (__attribute__((address_space(1))) void*)(uintptr_t)g,
        (__attribute__((address_space(3))) void*)(uintptr_t)lds,
        16, 0, 0);
}

// compile-time vmcnt wait + barrier
template<int N>
__device__ __forceinline__ void waitvm_barrier() {
    if constexpr (N == 0)       asm volatile("s_waitcnt vmcnt(0)\n\ts_barrier" ::: "memory");
    else if constexpr (N == 4)  asm volatile("s_waitcnt vmcnt(4)\n\ts_barrier" ::: "memory");
    else if constexpr (N == 6)  asm volatile("s_waitcnt vmcnt(6)\n\ts_barrier" ::: "memory");
    else if constexpr (N == 8)  asm volatile("s_waitcnt vmcnt(8)\n\ts_barrier" ::: "memory");
    else if constexpr (N == 12) asm volatile("s_waitcnt vmcnt(12)\n\ts_barrier" ::: "memory");
    else if constexpr (N == 16) asm volatile("s_waitcnt vmcnt(16)\n\ts_barrier" ::: "memory");
    else static_assert(N == 0, "unsupported vmcnt");
}

// runtime (wave-uniform) vmcnt wait + barrier for the drain tail
__device__ __forceinline__ void waitvm_barrier_rt(int n) {
    switch (n) {
    case 12: asm volatile("s_waitcnt vmcnt(12)\n\ts_barrier" ::: "memory"); break;
    case 8:  asm volatile("s_waitcnt vmcnt(8)\n\ts_barrier"  ::: "memory"); break;
    case 6:  asm volatile("s_waitcnt vmcnt(6)\n\ts_barrier"  ::: "memory"); break;
    case 4:  asm volatile("s_waitcnt vmcnt(4)\n\ts_barrier"  ::: "memory"); break;
    default: asm volatile("s_waitcnt vmcnt(0)\n\ts_barrier"  ::: "memory"); break;
    }
}

// ---------------- prep: weight transposes (blocks 0..3071) + ln1 (3072..3327)
__global__ void prep_kernel(const float* __restrict__ wq, const float* __restrict__ wk,
                            const float* __restrict__ wv, const float* __restrict__ w_proj,
                            const float* __restrict__ w1, const float* __restrict__ w2,
                            bf16_t* __restrict__ WQKVT, bf16_t* __restrict__ WPROJT,
                            bf16_t* __restrict__ W1T, bf16_t* __restrict__ W2T,
                            const float* __restrict__ x, const float* __restrict__ g1,
                            const float* __restrict__ be1, bf16_t* __restrict__ HB)
{
    __shared__ __align__(16) char psm[33024];
    const int tid = threadIdx.x;
    if (blockIdx.x < 3072) {
        // ---- weight transpose + cast, fragment-tiled coalesced writes ----
        float (*tile)[65] = (float(*)[65])psm;
        const int idx = blockIdx.x;
        const float* in; bf16_t* out; int R, C, rt, ct; long nrow0;
        if (idx < 768) {
            const int z = idx >> 8;
            const int hd = (idx >> 4) & 15;
            rt = idx & 15; ct = 0; R = 1024; C = 64;
            in  = (z == 0 ? wq : z == 1 ? wk : wv) + hd * 65536;
            out = WQKVT; nrow0 = z * 1024 + hd * 64;
        } else if (idx < 1024) {
            const int t = idx - 768; rt = t & 15; ct = t >> 4; R = 1024; C = 1024;
            in = w_proj; out = WPROJT; nrow0 = 0;
        } else if (idx < 2048) {
            const int t = idx - 1024; rt = t & 15; ct = t >> 4; R = 1024; C = 4096;
            in = w1; out = W1T; nrow0 = 0;
        } else {
            const int t = idx - 2048; rt = t & 63; ct = t >> 6; R = 4096; C = 1024;
            in = w2; out = W2T; nrow0 = 0;
        }
        const int r0 = rt * 64, c0 = ct * 64;
        const int tr = tid >> 4;
        const int tc = (tid & 15) * 4;
#pragma unroll
        for (int rr = 0; rr < 4; rr++) {
            const int r = tr + rr * 16;
            const float4 v = *(const float4*)&in[(long)(r0 + r) * C + c0 + tc];
            tile[r][tc + 0] = v.x; tile[r][tc + 1] = v.y;
            tile[r][tc + 2] = v.z; tile[r][tc + 3] = v.w;
        }
        __syncthreads();
        const int KT = R >> 5;
        const int w = tid >> 6, l = tid & 63;
        const int c = l >> 4, rr2 = l & 15;
#pragma unroll
        for (int it = 0; it < 2; ++it) {
            const int t8 = it * 4 + w;
            const int kt = t8 >> 2;
            const int nb = t8 & 3;
            const long n = nrow0 + c0 + nb * 16 + rr2;
            const int k = r0 + kt * 32 + c * 8;
            bf16x8 o;
#pragma unroll
            for (int e = 0; e < 8; e++)
                o[e] = (bf16_t)tile[kt * 32 + c * 8 + e][nb * 16 + rr2];
            *(bf16x8*)&out[ftaddr((int)n, k, KT)] = o;
        }
    } else {
        // ---- layernorm, 16 rows/block, tiled-coalesced bf16 out ----
        bf16_t (*ybuf)[1032] = (bf16_t(*)[1032])psm;
        const int wave = tid >> 6, lane = tid & 63;
        const int rb = blockIdx.x - 3072;
        float4 gvv[4], bvv[4];
#pragma unroll
        for (int j = 0; j < 4; j++) {
            gvv[j] = ((const float4*)g1)[lane + j * 64];
            bvv[j] = ((const float4*)be1)[lane + j * 64];
        }
#pragma unroll
        for (int rr = 0; rr < 4; ++rr) {
            const int lrow = wave * 4 + rr;
            const float* xr = x + (size_t)(rb * 16 + lrow) * 1024;
            float4 v[4];
            float s = 0.f, s2 = 0.f;
#pragma unroll
            for (int j = 0; j < 4; j++) {
                v[j] = ((const float4*)xr)[lane + j * 64];
                s  += v[j].x + v[j].y + v[j].z + v[j].w;
                s2 += v[j].x * v[j].x + v[j].y * v[j].y + v[j].z * v[j].z + v[j].w * v[j].w;
            }
#pragma unroll
            for (int off = 32; off >= 1; off >>= 1) {
                s  += __shfl_xor(s, off);
                s2 += __shfl_xor(s2, off);
            }
            const float mu = s * (1.0f / 1024.0f);
            const float rs = rsqrtf(fmaxf(s2 * (1.0f / 1024.0f) - mu * mu, 0.f) + 1e-5f);
#pragma unroll
            for (int j = 0; j < 4; j++) {
                bf16x4 o;
                o[0] = (bf16_t)((v[j].x - mu) * rs * gvv[j].x + bvv[j].x);
                o[1] = (bf16_t)((v[j].y - mu) * rs * gvv[j].y + bvv[j].y);
                o[2] = (bf16_t)((v[j].z - mu) * rs * gvv[j].z + bvv[j].z);
                o[3] = (bf16_t)((v[j].w - mu) * rs * gvv[j].w + bvv[j].w);
                *(bf16x4*)&ybuf[lrow][(lane + j * 64) * 4] = o;
            }
        }
        __syncthreads();
        bf16_t* outBase = HB + (size_t)rb * 32 * 512;
#pragma unroll
        for (int it = 0; it < 8; ++it) {
            const int s = it * 256 + tid;
            const int kt = s >> 6, c = (s >> 4) & 3, rr2 = s & 15;
            const bf16x8 val = *(const bf16x8*)&ybuf[rr2][kt * 32 + c * 8];
            *(bf16x8*)&outBase[(size_t)s * 8] = val;
        }
    }
}

// ---------------- double layernorm: ln(ln(x)), tiled-coalesced out ------
__global__ void ln2x_kernel(const float* __restrict__ x, const float* __restrict__ g,
                            const float* __restrict__ b, bf16_t* __restrict__ outb)
{
    __shared__ __align__(16) bf16_t ybuf[16][1032];
    const int tid = threadIdx.x, wave = tid >> 6, lane = tid & 63;
    const int rb = blockIdx.x;
    float4 gvv[4], bvv[4];
#pragma unroll
    for (int j = 0; j < 4; j++) {
        gvv[j] = ((const float4*)g)[lane + j * 64];
        bvv[j] = ((const float4*)b)[lane + j * 64];
    }
#pragma unroll
    for (int rr = 0; rr < 4; ++rr) {
        const int lrow = wave * 4 + rr;
        const float* xr = x + (size_t)(rb * 16 + lrow) * 1024;
        float4 v[4];
        float s = 0.f, s2 = 0.f;
#pragma unroll
        for (int j = 0; j < 4; j++) {
            v[j] = ((const float4*)xr)[lane + j * 64];
            s  += v[j].x + v[j].y + v[j].z + v[j].w;
            s2 += v[j].x * v[j].x + v[j].y * v[j].y + v[j].z * v[j].z + v[j].w * v[j].w;
        }
#pragma unroll
        for (int off = 32; off >= 1; off >>= 1) {
            s  += __shfl_xor(s, off);
            s2 += __shfl_xor(s2, off);
        }
        float mu = s * (1.0f / 1024.0f);
        float rs = rsqrtf(fmaxf(s2 * (1.0f / 1024.0f) - mu * mu, 0.f) + 1e-5f);
        s = 0.f; s2 = 0.f;
#pragma unroll
        for (int j = 0; j < 4; j++) {
            v[j].x = (v[j].x - mu) * rs * gvv[j].x + bvv[j].x;
            v[j].y = (v[j].y - mu) * rs * gvv[j].y + bvv[j].y;
            v[j].z = (v[j].z - mu) * rs * gvv[j].z + bvv[j].z;
            v[j].w = (v[j].w - mu) * rs * gvv[j].w + bvv[j].w;
            s  += v[j].x + v[j].y + v[j].z + v[j].w;
            s2 += v[j].x * v[j].x + v[j].y * v[j].y + v[j].z * v[j].z + v[j].w * v[j].w;
        }
#pragma unroll
        for (int off = 32; off >= 1; off >>= 1) {
            s  += __shfl_xor(s, off);
            s2 += __shfl_xor(s2, off);
        }
        mu = s * (1.0f / 1024.0f);
        rs = rsqrtf(fmaxf(s2 * (1.0f / 1024.0f) - mu * mu, 0.f) + 1e-5f);
#pragma unroll
        for (int j = 0; j < 4; j++) {
            bf16x4 o;
            o[0] = (bf16_t)((v[j].x - mu) * rs * gvv[j].x + bvv[j].x);
            o[1] = (bf16_t)((v[j].y - mu) * rs * gvv[j].y + bvv[j].y);
            o[2] = (bf16_t)((v[j].z - mu) * rs * gvv[j].z + bvv[j].z);
            o[3] = (bf16_t)((v[j].w - mu) * rs * gvv[j].w + bvv[j].w);
            *(bf16x4*)&ybuf[lrow][(lane + j * 64) * 4] = o;
        }
    }
    __syncthreads();
    bf16_t* outBase = outb + (size_t)rb * 32 * 512;
#pragma unroll
    for (int it = 0; it < 8; ++it) {
        const int s = it * 256 + tid;
        const int kt = s >> 6, c = (s >> 4) & 3, rr2 = s & 15;
        const bf16x8 val = *(const bf16x8*)&ybuf[rr2][kt * 32 + c * 8];
        *(bf16x8*)&outBase[(size_t)s * 8] = val;
    }
}

// ---------------- reg-A GEMM (proj, FF2): 128x64 tile, B-only LDS --------
// DEEP=4: exact R9-verified schedule (FF2 41.8us). DEEP=8 (FF2 only this
// round): SAME per-slot fence structure, A prefetched 8 slots ahead into
// R[8][2] (static-indexed via unrolled halves). Ledger: 3 VMEM/slot;
// iter-top vmcnt(12)+barrier proves B(t..t+3) (staged 8 slots back, all
// waves) and A(t..t+3); per-slot vmcnt(22) = near-no-op backstop + sched
// fence. A slack 8 slots ~ 1000cy ~ HBM miss latency (FF1B 32MB, not
// L2-resident — R9's 4-slot slack left ~30% of miss latency exposed).
template<int EPI, int DEEP>
__global__ __launch_bounds__(256, 2)
void gemm_ra(const bf16_t* __restrict__ A, const bf16_t* __restrict__ Bt,
             const int K, const float* __restrict__ bias,
             const float* __restrict__ resid, float* __restrict__ outf,
             const int Nout)
{
    constexpr int D = 12;
    __shared__ __align__(16) bf16_t Bs[D * 2048];   // 48 KB
    const int tid = threadIdx.x, wave = tid >> 6, lane = tid & 63;
    const int bm = blockIdx.x * BM, bn = blockIdx.y * 64;
    const int KT = K >> 5;
    const int NT = K >> 5;          // 32 (proj) or 128 (FF2); mult of 8
    const int NTm = NT - 1;

    floatx4 acc[2][4];
#pragma unroll
    for (int i = 0; i < 2; i++)
#pragma unroll
        for (int j = 0; j < 4; j++) acc[i][j] = (floatx4){0.f, 0.f, 0.f, 0.f};

    const bf16_t* gA0 = A + ((size_t)(bm / 16 + wave * 2 + 0) * KT) * 512 + lane * 8;
    const bf16_t* gA1 = A + ((size_t)(bm / 16 + wave * 2 + 1) * KT) * 512 + lane * 8;
    const bf16_t* gB  = Bt + ((size_t)(bn / 16 + wave) * KT) * 512 + lane * 8;

    auto stageB = [&](int t, int b) {
        gload16(gB + (size_t)t * 512, Bs + b * 2048 + wave * 512);
    };
    auto loadA = [&](bf16x8& r0, bf16x8& r1, int t) {
        const bf16_t* p0 = gA0 + (size_t)t * 512;
        const bf16_t* p1 = gA1 + (size_t)t * 512;
        asm volatile("global_load_dwordx4 %0, %1, off"
                     : "=&v"(r0) : "v"(p0) : "memory");
        asm volatile("global_load_dwordx4 %0, %1, off"
                     : "=&v"(r1) : "v"(p1) : "memory");
    };
    auto computeS = [&](const bf16x8& a0, const bf16x8& a1, int b) {
        bf16x8 bfv[4];
#pragma unroll
        for (int j = 0; j < 4; j++)
            bfv[j] = *(const bf16x8*)&Bs[b * 2048 + j * 512 + lane * 8];
#pragma unroll
        for (int j = 0; j < 4; j++) {
            acc[0][j] = __builtin_amdgcn_mfma_f32_16x16x32_bf16(a0, bfv[j], acc[0][j], 0, 0, 0);
            acc[1][j] = __builtin_amdgcn_mfma_f32_16x16x32_bf16(a1, bfv[j], acc[1][j], 0, 0, 0);
        }
    };

    if constexpr (DEEP == 4) {
        // ---- exact R8/R9-verified schedule ----
        bf16x8 R[4][2];
#pragma unroll
        for (int i = 0; i < 4; i++) loadA(R[i][0], R[i][1], i);
#pragma unroll
        for (int s = 0; s < 8; s++) stageB(s, s);
        asm volatile("s_waitcnt vmcnt(4)\n\ts_barrier" ::: "memory");

        int bu = 0;
        const int NTI = NT >> 2;
        for (int T = 0; T < NTI; T++) {
            const int t = T << 2;
            if (T) asm volatile("s_waitcnt vmcnt(12)\n\ts_barrier" ::: "memory");
#pragma unroll
            for (int i = 0; i < 4; i++) {
                int bs = bu + 8 + i; if (bs >= D) bs -= D;
                stageB((t + 8 + i) & NTm, bs);
                asm volatile("s_waitcnt vmcnt(10)" ::: "memory");
                __builtin_amdgcn_sched_barrier(0);
                int bc = bu + i; if (bc >= D) bc -= D;
                computeS(R[i][0], R[i][1], bc);
                loadA(R[i][0], R[i][1], (t + 4 + i) & NTm);
            }
            bu += 4; if (bu >= D) bu -= D;
        }
        asm volatile("s_waitcnt vmcnt(0)" ::: "memory");
    } else {
        // ---- DEEP=8: R9 fence structure, A prefetched 8 slots ahead ----
        bf16x8 R[8][2];
#pragma unroll
        for (int i = 0; i < 4; i++) {
            stageB(i, i);
            loadA(R[i][0], R[i][1], i);
        }
#pragma unroll
        for (int i = 0; i < 4; i++) {
            stageB(4 + i, 4 + i);
            loadA(R[4 + i][0], R[4 + i][1], 4 + i);
        }
        int bu = 0;
        const int NU = NT >> 3;
        for (int U = 0; U < NU; U++) {
            const int t = U << 3;
#pragma unroll
            for (int hf = 0; hf < 2; hf++) {
                const int th = t + hf * 4;
                asm volatile("s_waitcnt vmcnt(12)\n\ts_barrier" ::: "memory");
                __builtin_amdgcn_sched_barrier(0);
#pragma unroll
                for (int i = 0; i < 4; i++) {
                    int bs = bu + 8 + i; if (bs >= D) bs -= D;
                    stageB((th + 8 + i) & NTm, bs);
                    asm volatile("s_waitcnt vmcnt(22)" ::: "memory");
                    __builtin_amdgcn_sched_barrier(0);
                    int bc = bu + i; if (bc >= D) bc -= D;
                    computeS(R[hf * 4 + i][0], R[hf * 4 + i][1], bc);
                    loadA(R[hf * 4 + i][0], R[hf * 4 + i][1], (th + 8 + i) & NTm);
                }
                bu += 4; if (bu >= D) bu -= D;
            }
        }
        asm volatile("s_waitcnt vmcnt(0)" ::: "memory");
    }

    const int er = (lane >> 4) * 4, ec = lane & 15;
#pragma unroll
    for (int i = 0; i < 2; i++) {
#pragma unroll
        for (int j = 0; j < 4; j++) {
            const int col = bn + j * 16 + ec;
#pragma unroll
            for (int r = 0; r < 4; r++) {
                const int row = bm + wave * 32 + i * 16 + er + r;
                const size_t idx = (size_t)row * Nout + col;
                outf[idx] = acc[i][j][r] + bias[col] + resid[idx];
            }
        }
    }
}

// ---------------- bf16 MFMA GEMM (QKV, FF1) ------------------------------
// BNt=128 (QKV): 2x2 waves, 4x4 frags, DEPTH=5 (80KB, 2/CU).
// BNt=256 (FF1): 2x2 waves, 4x8 frags, DEPTH=3 (72KB, 2/CU).
template<int EPI, int BNt, int DEPTH>
__global__ __launch_bounds__(256, 2)
void gemm_bt(const bf16_t* __restrict__ A, const bf16_t* __restrict__ Bt,
             const int K,
             const float* __restrict__ bias, const float* __restrict__ resid,
             float* __restrict__ outf, bf16_t* __restrict__ outb,
             bf16_t* __restrict__ aux1, bf16_t* __restrict__ aux2,
             const int Nout)
{
    constexpr int NFRAG = (BNt == 256) ? 8 : 4;    // B-frags per wave
    constexpr int AI    = 4;                       // A-frags per wave
    constexpr int LPS   = (BNt == 256) ? 6 : 4;
    constexpr int BFT   = BNt / 16;                // B ftiles per stage
    constexpr int ASZ = DEPTH * 8 * 512;
    constexpr int BSZ = DEPTH * BFT * 512;
    __shared__ __align__(16) bf16_t smem[ASZ + BSZ];
    bf16_t* Asb = smem;
    bf16_t* Bsb = smem + ASZ;
    const int tid  = threadIdx.x;
    const int wave = tid >> 6, lane = tid & 63;
    const int wr = wave >> 1, wc = wave & 1;  // 2x2 wave grid
    const int bm = blockIdx.x * BM, bn = blockIdx.y * BNt;
    const int KT = K >> 5;

    floatx4 acc[AI][NFRAG];
#pragma unroll
    for (int i = 0; i < AI; i++)
#pragma unroll
        for (int j = 0; j < NFRAG; j++) acc[i][j] = (floatx4){0.f, 0.f, 0.f, 0.f};

    const bf16_t* gA0 = A + ((size_t)(bm / 16 + wave * 2 + 0) * KT) * 512 + lane * 8;
    const bf16_t* gA1 = A + ((size_t)(bm / 16 + wave * 2 + 1) * KT) * 512 + lane * 8;
    const int lA0 = (wave * 2 + 0) * 512;
    const int lA1 = (wave * 2 + 1) * 512;

    const bf16_t* gB[4];
    if (BNt == 256) {
#pragma unroll
        for (int q = 0; q < 4; q++)
            gB[q] = Bt + ((size_t)(bn / 16 + wave * 4 + q) * KT) * 512 + lane * 8;
    } else {
        gB[0] = Bt + ((size_t)(bn / 16 + wave * 2 + 0) * KT) * 512 + lane * 8;
        gB[1] = Bt + ((size_t)(bn / 16 + wave * 2 + 1) * KT) * 512 + lane * 8;
    }

    auto stage = [&](int t, int bu) {
        const size_t off = (size_t)t * 512;
        gload16(gA0 + off, Asb + bu * 4096 + lA0);
        gload16(gA1 + off, Asb + bu * 4096 + lA1);
        if (BNt == 256) {
#pragma unroll
            for (int q = 0; q < 4; q++)
                gload16(gB[q] + off, Bsb + bu * (BFT * 512) + (wave * 4 + q) * 512);
        } else {
            gload16(gB[0] + off, Bsb + bu * 4096 + lA0);
            gload16(gB[1] + off, Bsb + bu * 4096 + lA1);
        }
    };

    auto compute = [&](int bu) {
        bf16x8 af[AI], bfv[NFRAG];
#pragma unroll
        for (int i = 0; i < AI; i++)
            af[i] = *(const bf16x8*)&Asb[bu * 4096 + (wr * 4 + i) * 512 + lane * 8];
#pragma unroll
        for (int j = 0; j < NFRAG; j++)
            bfv[j] = *(const bf16x8*)&Bsb[bu * (BFT * 512) + (wc * NFRAG + j) * 512 + lane * 8];
#pragma unroll
        for (int i = 0; i < AI; i++)
#pragma unroll
            for (int j = 0; j < NFRAG; j++)
                acc[i][j] = __builtin_amdgcn_mfma_f32_16x16x32_bf16(af[i], bfv[j], acc[i][j], 0, 0, 0);
    };

    const int NT = K / BK;
    // ---- every-iter barrier pipeline ----
#pragma unroll
    for (int i = 0; i < DEPTH - 1; ++i) stage(i, i);
    int bu = 0;
    for (int t = 0; t <= NT - DEPTH; ++t) {
        waitvm_barrier<LPS * (DEPTH - 2)>();
        stage(t + DEPTH - 1, bu == 0 ? DEPTH - 1 : bu - 1);
        compute(bu);
        bu = (bu + 1 == DEPTH) ? 0 : bu + 1;
    }
#pragma unroll
    for (int j = DEPTH - 2; j >= 0; --j) {
        waitvm_barrier_rt(LPS * j);
        compute(bu);
        bu = (bu + 1 == DEPTH) ? 0 : bu + 1;
    }

    const int er = (lane >> 4) * 4, ec = lane & 15;
    if constexpr (EPI == 0) {
        if (bn >= 2048) {
            // V-block: LDS transpose then coalesced [d][t] writes
            __syncthreads();                      // staging LDS now dead
            bf16_t* scr = smem;                   // 128 x 136 (pad) bf16 = 34 KB
#pragma unroll
            for (int i = 0; i < AI; i++)
#pragma unroll
                for (int j = 0; j < NFRAG; j++)
#pragma unroll
                    for (int r = 0; r < 4; r++)
                        scr[((wc * NFRAG + j) * 16 + ec) * 136 + (wr * 4 + i) * 16 + er + r] =
                            (bf16_t)acc[i][j][r];
            __syncthreads();
            const int bq = bm >> 10, tmod = bm & 1023, h0 = (bn - 2048) >> 6;
#pragma unroll
            for (int it = 0; it < 8; ++it) {
                const int c = it * 256 + tid;
                const int dl = c >> 4, t16 = c & 15;
                const bf16x8 val = *(const bf16x8*)&scr[dl * 136 + t16 * 8];
                const int h = h0 + (dl >> 6), dd = dl & 63;
                *(bf16x8*)&aux2[(size_t)((bq * 16 + h) * 64 + dd) * 1024 + tmod + t16 * 8] = val;
            }
            return;
        }
    }
#pragma unroll
    for (int i = 0; i < AI; i++) {
#pragma unroll
        for (int j = 0; j < NFRAG; j++) {
            const int col = bn + (wc * NFRAG + j) * 16 + ec;
#pragma unroll
            for (int r = 0; r < 4; r++) {
                const int row = bm + (wr * 4 + i) * 16 + er + r;
                const float v = acc[i][j][r];
                if (EPI == 0) {
                    const int b = row >> 10, t = row & 1023;
                    if (col < 1024) {
                        const int h = col >> 6, d = col & 63;
                        outb[(size_t)((b * 16 + h) * 1024 + t) * 64 + d] = (bf16_t)v;
                    } else {
                        const int c2 = col - 1024, h = c2 >> 6, d = c2 & 63;
                        aux1[(size_t)((b * 16 + h) * 1024 + t) * 64 + d] = (bf16_t)v;
                    }
                } else if (EPI == 2) {
                    outb[ftaddr(row, col, Nout >> 5)] = (bf16_t)fmaxf(v + bias[col], 0.f);
                }
            }
        }
    }
}

// ---------------- flash attention (R9-verified: coalesced swizzled staging)
__global__ __launch_bounds__(256, 4)
void attn_kernel(const bf16_t* __restrict__ Q, const bf16_t* __restrict__ Kg,
                 const bf16_t* __restrict__ Vt, bf16_t* __restrict__ Og)
{
    __shared__ __align__(16) bf16_t Ks[2][4096];
    __shared__ __align__(16) bf16_t Vs[2][4096];
    __shared__ __align__(16) bf16_t Ps[4][1024];
    const int tid = threadIdx.x, wave = tid >> 6, lane = tid & 63;
    const int lin = blockIdx.x + (blockIdx.y << 4);
    const int xcd = lin & 7, idx = lin >> 3;
    const int bh = xcd * 8 + (idx >> 4);
    const int qt = idx & 15;
    const int b = bh >> 4, h = bh & 15;
    const int q0 = qt * 64 + wave * 16;
    const bf16_t* Qb = Q + (size_t)bh * 65536;
    const char* Kb = (const char*)(Kg + (size_t)bh * 65536);
    const char* Vb = (const char*)(Vt + (size_t)bh * 65536);
    const int fr = lane & 15, g = lane >> 4, fk = g * 8;

    const bf16x8 qf0 = *(const bf16x8*)&Qb[(size_t)(q0 + fr) * 64 + fk];
    const bf16x8 qf1 = *(const bf16x8*)&Qb[(size_t)(q0 + fr) * 64 + 32 + fk];

    floatx4 o[4];
#pragma unroll
    for (int dt = 0; dt < 4; dt++) o[dt] = (floatx4){0.f, 0.f, 0.f, 0.f};
    float lsum[4] = {0.f, 0.f, 0.f, 0.f};
    bf16_t* pw = &Ps[wave][0];
    const float sscale = 0.125f * 1.44269504088896f;

    const int sub = lane >> 3;               // row within 8-row group
    const int cc  = (lane & 7) ^ sub;        // swizzled 16B chunk (involution)
    auto stage = [&](int s0, int bu) {
#pragma unroll
        for (int t = 0; t < 2; t++) {
            const int j = wave * 2 + t;      // 8-row slot 0..7
            const int row = j * 8 + sub;     // 0..63
            gload16(Kb + (size_t)(s0 + row) * 128 + cc * 16, &Ks[bu][j * 512]);
            gload16(Vb + (size_t)row * 2048 + (size_t)s0 * 2 + cc * 16, &Vs[bu][j * 512]);
        }
    };

    stage(0, 0);
    int bu = 0;
    for (int it = 0; it < 16; ++it) {
        __syncthreads();
        if (it < 15) stage((it + 1) * 64, bu ^ 1);
        const bf16_t* Kl = Ks[bu];
        const bf16_t* Vl = Vs[bu];

        floatx4 sacc[4];
#pragma unroll
        for (int ss = 0; ss < 4; ss++) sacc[ss] = (floatx4){0.f, 0.f, 0.f, 0.f};
        __builtin_amdgcn_s_setprio(1);
#pragma unroll
        for (int ss = 0; ss < 4; ss++) {
#pragma unroll
            for (int c = 0; c < 2; c++) {
                const int ch = c * 4 + g;
                const bf16x8 qf = (c == 0) ? qf0 : qf1;
                const bf16x8 kf = *(const bf16x8*)
                    &Kl[(ss * 16 + fr) * 64 + ((ch ^ (fr & 7)) << 3)];
                sacc[ss] = __builtin_amdgcn_mfma_f32_16x16x32_bf16(qf, kf, sacc[ss], 0, 0, 0);
            }
        }
        __builtin_amdgcn_s_setprio(0);
#pragma unroll
        for (int ss = 0; ss < 2; ss++) {
#pragma unroll
            for (int r = 0; r < 4; r++) {
                const float p = __builtin_amdgcn_exp2f(sacc[ss][r] * sscale);
                lsum[r] += p;
                const int q = g * 4 + r;
                pw[(ss * 2 + (fr >> 3)) * 128 + q * 8 + (fr & 7)] = (bf16_t)p;
            }
        }
        asm volatile("s_waitcnt lgkmcnt(0)" ::: "memory");
#pragma unroll
        for (int ss = 2; ss < 4; ss++) {
#pragma unroll
            for (int r = 0; r < 4; r++) {
                const float p = __builtin_amdgcn_exp2f(sacc[ss][r] * sscale);
                lsum[r] += p;
                const int q = g * 4 + r;
                pw[(ss * 2 + (fr >> 3)) * 128 + q * 8 + (fr & 7)] = (bf16_t)p;
            }
        }
        {
            const int ch = g;
            const bf16x8 pf = *(const bf16x8*)&pw[ch * 128 + fr * 8];
            __builtin_amdgcn_s_setprio(1);
#pragma unroll
            for (int dt = 0; dt < 4; dt++) {
                const bf16x8 vf = *(const bf16x8*)
                    &Vl[(dt * 16 + fr) * 64 + ((ch ^ (fr & 7)) << 3)];
                o[dt] = __builtin_amdgcn_mfma_f32_16x16x32_bf16(pf, vf, o[dt], 0, 0, 0);
            }
            __builtin_amdgcn_s_setprio(0);
        }
        asm volatile("s_waitcnt lgkmcnt(0)" ::: "memory");
        {
            const int ch = 4 + g;
            const bf16x8 pf = *(const bf16x8*)&pw[ch * 128 + fr * 8];
            __builtin_amdgcn_s_setprio(1);
#pragma unroll
            for (int dt = 0; dt < 4; dt++) {
                const bf16x8 vf = *(const bf16x8*)
                    &Vl[(dt * 16 + fr) * 64 + ((ch ^ (fr & 7)) << 3)];
                o[dt] = __builtin_amdgcn_mfma_f32_16x16x32_bf16(pf, vf, o[dt], 0, 0, 0);
            }
            __builtin_amdgcn_s_setprio(0);
        }
        asm volatile("" ::: "memory");
        bu ^= 1;
    }
#pragma unroll
    for (int r = 0; r < 4; r++) {
        float l = lsum[r];
        l += __shfl_xor(l, 1);
        l += __shfl_xor(l, 2);
        l += __shfl_xor(l, 4);
        l += __shfl_xor(l, 8);
        lsum[r] = 1.0f / l;
    }
    const int tq = q0 + g * 4;
#pragma unroll
    for (int dt = 0; dt < 4; dt++) {
#pragma unroll
        for (int r = 0; r < 4; r++) {
            const int m = b * 1024 + tq + r;
            const int k = h * 64 + dt * 16 + fr;
            Og[ftaddr(m, k, 32)] = (bf16_t)(o[dt][r] * lsum[r]);
        }
    }
}

// -------------------------------------------------------------------------
extern "C" void kernel_launch(void* const* d_in, const int* in_sizes, int n_in,
                              void* d_out, int out_size, void* d_ws, size_t ws_size,
                              hipStream_t stream)
{
    const float* x      = (const float*)d_in[0];
    const float* wq     = (const float*)d_in[1];
    const float* wk     = (const float*)d_in[2];
    const float* wv     = (const float*)d_in[3];
    const float* w_proj = (const float*)d_in[4];
    const float* b_proj = (const float*)d_in[5];
    const float* w1     = (const float*)d_in[6];
    const float* b1     = (const float*)d_in[7];
    const float* w2     = (const float*)d_in[8];
    const float* b2     = (const float*)d_in[9];
    const float* g1     = (const float*)d_in[10];
    const float* be1    = (const float*)d_in[11];
    const float* g2     = (const float*)d_in[12];
    const float* be2    = (const float*)d_in[13];
    float* out = (float*)d_out;
    char* ws = (char*)d_ws;

    bf16_t* WQKVT = (bf16_t*)(ws + 0x0000000);  // [3072,1024] tiled, 6 MB
    bf16_t* WPROJT= (bf16_t*)(ws + 0x0600000);  // [1024,1024] tiled, 2 MB
    bf16_t* W1T   = (bf16_t*)(ws + 0x0800000);  // [4096,1024] tiled, 8 MB
    bf16_t* W2T   = (bf16_t*)(ws + 0x1000000);  // [1024,4096] tiled, 8 MB
    bf16_t* HB    = (bf16_t*)(ws + 0x1800000);  // ln1 out tiled, 8 MB
    bf16_t* Qb    = (bf16_t*)(ws + 0x2000000);  // [BH,T,64] bf16, 8 MB
    bf16_t* Kb    = (bf16_t*)(ws + 0x2800000);  // [BH,T,64] bf16, 8 MB
    bf16_t* Vtb   = (bf16_t*)(ws + 0x3000000);  // [BH,64,T] bf16, 8 MB
    bf16_t* AO    = (bf16_t*)(ws + 0x3800000);  // attn out tiled, 8 MB
    float*  X2    = (float*)(ws + 0x4000000);   // x+sa fp32 row-major, 16 MB
    bf16_t* TB    = (bf16_t*)(ws + 0x2800000);  // ln2(ln2) tiled (reuses Kb), 8 MB
    bf16_t* FF1B  = (bf16_t*)(ws + 0x5000000);  // [4096,4096] tiled, 32 MB

    dim3 blk(256);
    prep_kernel<<<3328, blk, 0, stream>>>(wq, wk, wv, w_proj, w1, w2,
                                          WQKVT, WPROJT, W1T, W2T,
                                          x, g1, be1, HB);
    gemm_bt<0, 128, 5><<<dim3(32, 24), blk, 0, stream>>>(HB, WQKVT, 1024, nullptr, nullptr,
                                                         nullptr, Qb, Kb, Vtb, 3072);
    attn_kernel<<<dim3(16, 64), blk, 0, stream>>>(Qb, Kb, Vtb, AO);
    // proj: reg-A GEMM, proven DEEP=4 schedule
    gemm_ra<1, 4><<<dim3(32, 16), blk, 0, stream>>>(AO, WPROJT, 1024, b_proj, x, X2, 1024);
    ln2x_kernel<<<256, blk, 0, stream>>>(X2, g2, be2, TB);
    // FF1: back on gemm_bt 256-tile (proven 42.3us; ra port was 52.2)
    gemm_bt<2, 256, 3><<<dim3(32, 16), blk, 0, stream>>>(TB, W1T, 1024, b1, nullptr,
                                                         nullptr, FF1B, nullptr, nullptr, 4096);
    // FF2: reg-A GEMM, DEEP=8 (isolated variable this round)
    gemm_ra<3, 8><<<dim3(32, 16), blk, 0, stream>>>(FF1B, W2T, 4096, b2, X2, out, 1024);
}

// Round 12
// 287.343 us; speedup vs baseline: 1.0545x; 1.0280x over previous
//
#include <hip/hip_runtime.h>
#include <hip/hip_bf16.h>
#include <math.h>
#include <stdint.h>

typedef __bf16 bf16_t;
typedef __bf16 bf16x4 __attribute__((ext_vector_type(4)));
typedef __bf16 bf16x8 __attribute__((ext_vector_type(8)));
typedef float floatx4 __attribute__((ext_vector_type(4)));

#define BM 128
#define BK 32

// fragment-tiled address: 16-row x 32-k tiles, chunk-major inside
__device__ __forceinline__ size_t ftaddr(int m, int k, int KT) {
    return ((size_t)(m >> 4) * KT + (k >> 5)) * 512
         + (((k >> 3) & 3) * 16 + (m & 15)) * 8 + (k & 7);
}

__device__ __forceinline__ void gload16(const void* g, void* lds) {
    __builtin_amdgcn_global_load_lds(
        (__attribute__((address_space(1))) void*)(uintptr_t)g,
        (__attribute__((address_space(3))) void*)(uintptr_t)lds,
        16, 0, 0);
}

// compile-time vmcnt wait + barrier
template<int N>
__device__ __forceinline__ void waitvm_barrier() {
    if constexpr (N == 0)       asm volatile("s_waitcnt vmcnt(0)\n\ts_barrier" ::: "memory");
    else if constexpr (N == 4)  asm volatile("s_waitcnt vmcnt(4)\n\ts_barrier" ::: "memory");
    else if constexpr (N == 6)  asm volatile("s_waitcnt vmcnt(6)\n\ts_barrier" ::: "memory");
    else if constexpr (N == 8)  asm volatile("s_waitcnt vmcnt(8)\n\ts_barrier" ::: "memory");
    else if constexpr (N == 12) asm volatile("s_waitcnt vmcnt(12)\n\ts_barrier" ::: "memory");
    else if constexpr (N == 16) asm volatile("s_waitcnt vmcnt(16)\n\ts_barrier" ::: "memory");
    else static_assert(N == 0, "unsupported vmcnt");
}

// runtime (wave-uniform) vmcnt wait + barrier for the drain tail
__device__ __forceinline__ void waitvm_barrier_rt(int n) {
    switch (n) {
    case 12: asm volatile("s_waitcnt vmcnt(12)\n\ts_barrier" ::: "memory"); break;
    case 8:  asm volatile("s_waitcnt vmcnt(8)\n\ts_barrier"  ::: "memory"); break;
    case 6:  asm volatile("s_waitcnt vmcnt(6)\n\ts_barrier"  ::: "memory"); break;
    case 4:  asm volatile("s_waitcnt vmcnt(4)\n\ts_barrier"  ::: "memory"); break;
    default: asm volatile("s_waitcnt vmcnt(0)\n\ts_barrier"  ::: "memory"); break;
    }
}

// ---------------- prep: weight transposes (blocks 0..3071) + ln1 (3072..3327)
__global__ void prep_kernel(const float* __restrict__ wq, const float* __restrict__ wk,
                            const float* __restrict__ wv, const float* __restrict__ w_proj,
                            const float* __restrict__ w1, const float* __restrict__ w2,
                            bf16_t* __restrict__ WQKVT, bf16_t* __restrict__ WPROJT,
                            bf16_t* __restrict__ W1T, bf16_t* __restrict__ W2T,
                            const float* __restrict__ x, const float* __restrict__ g1,
                            const float* __restrict__ be1, bf16_t* __restrict__ HB)
{
    __shared__ __align__(16) char psm[33024];
    const int tid = threadIdx.x;
    if (blockIdx.x < 3072) {
        // ---- weight transpose + cast, fragment-tiled coalesced writes ----
        float (*tile)[65] = (float(*)[65])psm;
        const int idx = blockIdx.x;
        const float* in; bf16_t* out; int R, C, rt, ct; long nrow0;
        if (idx < 768) {
            const int z = idx >> 8;
            const int hd = (idx >> 4) & 15;
            rt = idx & 15; ct = 0; R = 1024; C = 64;
            in  = (z == 0 ? wq : z == 1 ? wk : wv) + hd * 65536;
            out = WQKVT; nrow0 = z * 1024 + hd * 64;
        } else if (idx < 1024) {
            const int t = idx - 768; rt = t & 15; ct = t >> 4; R = 1024; C = 1024;
            in = w_proj; out = WPROJT; nrow0 = 0;
        } else if (idx < 2048) {
            const int t = idx - 1024; rt = t & 15; ct = t >> 4; R = 1024; C = 4096;
            in = w1; out = W1T; nrow0 = 0;
        } else {
            const int t = idx - 2048; rt = t & 63; ct = t >> 6; R = 4096; C = 1024;
            in = w2; out = W2T; nrow0 = 0;
        }
        const int r0 = rt * 64, c0 = ct * 64;
        const int tr = tid >> 4;
        const int tc = (tid & 15) * 4;
#pragma unroll
        for (int rr = 0; rr < 4; rr++) {
            const int r = tr + rr * 16;
            const float4 v = *(const float4*)&in[(long)(r0 + r) * C + c0 + tc];
            tile[r][tc + 0] = v.x; tile[r][tc + 1] = v.y;
            tile[r][tc + 2] = v.z; tile[r][tc + 3] = v.w;
        }
        __syncthreads();
        const int KT = R >> 5;
        const int w = tid >> 6, l = tid & 63;
        const int c = l >> 4, rr2 = l & 15;
#pragma unroll
        for (int it = 0; it < 2; ++it) {
            const int t8 = it * 4 + w;
            const int kt = t8 >> 2;
            const int nb = t8 & 3;
            const long n = nrow0 + c0 + nb * 16 + rr2;
            const int k = r0 + kt * 32 + c * 8;
            bf16x8 o;
#pragma unroll
            for (int e = 0; e < 8; e++)
                o[e] = (bf16_t)tile[kt * 32 + c * 8 + e][nb * 16 + rr2];
            *(bf16x8*)&out[ftaddr((int)n, k, KT)] = o;
        }
    } else {
        // ---- layernorm, 16 rows/block, tiled-coalesced bf16 out ----
        bf16_t (*ybuf)[1032] = (bf16_t(*)[1032])psm;
        const int wave = tid >> 6, lane = tid & 63;
        const int rb = blockIdx.x - 3072;
        float4 gvv[4], bvv[4];
#pragma unroll
        for (int j = 0; j < 4; j++) {
            gvv[j] = ((const float4*)g1)[lane + j * 64];
            bvv[j] = ((const float4*)be1)[lane + j * 64];
        }
#pragma unroll
        for (int rr = 0; rr < 4; ++rr) {
            const int lrow = wave * 4 + rr;
            const float* xr = x + (size_t)(rb * 16 + lrow) * 1024;
            float4 v[4];
            float s = 0.f, s2 = 0.f;
#pragma unroll
            for (int j = 0; j < 4; j++) {
                v[j] = ((const float4*)xr)[lane + j * 64];
                s  += v[j].x + v[j].y + v[j].z + v[j].w;
                s2 += v[j].x * v[j].x + v[j].y * v[j].y + v[j].z * v[j].z + v[j].w * v[j].w;
            }
#pragma unroll
            for (int off = 32; off >= 1; off >>= 1) {
                s  += __shfl_xor(s, off);
                s2 += __shfl_xor(s2, off);
            }
            const float mu = s * (1.0f / 1024.0f);
            const float rs = rsqrtf(fmaxf(s2 * (1.0f / 1024.0f) - mu * mu, 0.f) + 1e-5f);
#pragma unroll
            for (int j = 0; j < 4; j++) {
                bf16x4 o;
                o[0] = (bf16_t)((v[j].x - mu) * rs * gvv[j].x + bvv[j].x);
                o[1] = (bf16_t)((v[j].y - mu) * rs * gvv[j].y + bvv[j].y);
                o[2] = (bf16_t)((v[j].z - mu) * rs * gvv[j].z + bvv[j].z);
                o[3] = (bf16_t)((v[j].w - mu) * rs * gvv[j].w + bvv[j].w);
                *(bf16x4*)&ybuf[lrow][(lane + j * 64) * 4] = o;
            }
        }
        __syncthreads();
        bf16_t* outBase = HB + (size_t)rb * 32 * 512;
#pragma unroll
        for (int it = 0; it < 8; ++it) {
            const int s = it * 256 + tid;
            const int kt = s >> 6, c = (s >> 4) & 3, rr2 = s & 15;
            const bf16x8 val = *(const bf16x8*)&ybuf[rr2][kt * 32 + c * 8];
            *(bf16x8*)&outBase[(size_t)s * 8] = val;
        }
    }
}

// ---------------- double layernorm: ln(ln(x)), tiled-coalesced out ------
__global__ void ln2x_kernel(const float* __restrict__ x, const float* __restrict__ g,
                            const float* __restrict__ b, bf16_t* __restrict__ outb)
{
    __shared__ __align__(16) bf16_t ybuf[16][1032];
    const int tid = threadIdx.x, wave = tid >> 6, lane = tid & 63;
    const int rb = blockIdx.x;
    float4 gvv[4], bvv[4];
#pragma unroll
    for (int j = 0; j < 4; j++) {
        gvv[j] = ((const float4*)g)[lane + j * 64];
        bvv[j] = ((const float4*)b)[lane + j * 64];
    }
#pragma unroll
    for (int rr = 0; rr < 4; ++rr) {
        const int lrow = wave * 4 + rr;
        const float* xr = x + (size_t)(rb * 16 + lrow) * 1024;
        float4 v[4];
        float s = 0.f, s2 = 0.f;
#pragma unroll
        for (int j = 0; j < 4; j++) {
            v[j] = ((const float4*)xr)[lane + j * 64];
            s  += v[j].x + v[j].y + v[j].z + v[j].w;
            s2 += v[j].x * v[j].x + v[j].y * v[j].y + v[j].z * v[j].z + v[j].w * v[j].w;
        }
#pragma unroll
        for (int off = 32; off >= 1; off >>= 1) {
            s  += __shfl_xor(s, off);
            s2 += __shfl_xor(s2, off);
        }
        float mu = s * (1.0f / 1024.0f);
        float rs = rsqrtf(fmaxf(s2 * (1.0f / 1024.0f) - mu * mu, 0.f) + 1e-5f);
        s = 0.f; s2 = 0.f;
#pragma unroll
        for (int j = 0; j < 4; j++) {
            v[j].x = (v[j].x - mu) * rs * gvv[j].x + bvv[j].x;
            v[j].y = (v[j].y - mu) * rs * gvv[j].y + bvv[j].y;
            v[j].z = (v[j].z - mu) * rs * gvv[j].z + bvv[j].z;
            v[j].w = (v[j].w - mu) * rs * gvv[j].w + bvv[j].w;
            s  += v[j].x + v[j].y + v[j].z + v[j].w;
            s2 += v[j].x * v[j].x + v[j].y * v[j].y + v[j].z * v[j].z + v[j].w * v[j].w;
        }
#pragma unroll
        for (int off = 32; off >= 1; off >>= 1) {
            s  += __shfl_xor(s, off);
            s2 += __shfl_xor(s2, off);
        }
        mu = s * (1.0f / 1024.0f);
        rs = rsqrtf(fmaxf(s2 * (1.0f / 1024.0f) - mu * mu, 0.f) + 1e-5f);
#pragma unroll
        for (int j = 0; j < 4; j++) {
            bf16x4 o;
            o[0] = (bf16_t)((v[j].x - mu) * rs * gvv[j].x + bvv[j].x);
            o[1] = (bf16_t)((v[j].y - mu) * rs * gvv[j].y + bvv[j].y);
            o[2] = (bf16_t)((v[j].z - mu) * rs * gvv[j].z + bvv[j].z);
            o[3] = (bf16_t)((v[j].w - mu) * rs * gvv[j].w + bvv[j].w);
            *(bf16x4*)&ybuf[lrow][(lane + j * 64) * 4] = o;
        }
    }
    __syncthreads();
    bf16_t* outBase = outb + (size_t)rb * 32 * 512;
#pragma unroll
    for (int it = 0; it < 8; ++it) {
        const int s = it * 256 + tid;
        const int kt = s >> 6, c = (s >> 4) & 3, rr2 = s & 15;
        const bf16x8 val = *(const bf16x8*)&ybuf[rr2][kt * 32 + c * 8];
        *(bf16x8*)&outBase[(size_t)s * 8] = val;
    }
}

// ---------------- reg-A GEMM (proj, FF2): 128x64 tile, B-only LDS --------
// A-frags are wave-private in the 128x64 tile -> load them global->VGPR
// directly (inline asm, deterministic vmcnt ledger). LDS holds only B
// (the true broadcast): 12-buffer ring, 48KB. Per-step LDS traffic drops
// 36KB -> 20KB. VMEM ledger: 12 ops/iter ([B,A,A]x4); iter-top vmcnt(12)
// proves B(t..t+3) (staged 2 iters back); per-slot vmcnt(10)+sched_barrier
// proves A(t+i) (loaded 1 iter back). R11 probe: deeper A-prefetch (8
// slots) is NULL — this DEEP=4 schedule is the verified-best form.
template<int EPI>
__global__ __launch_bounds__(256, 2)
void gemm_ra(const bf16_t* __restrict__ A, const bf16_t* __restrict__ Bt,
             const int K, const float* __restrict__ bias,
             const float* __restrict__ resid, float* __restrict__ outf,
             const int Nout)
{
    constexpr int D = 12;
    __shared__ __align__(16) bf16_t Bs[D * 2048];   // 48 KB
    const int tid = threadIdx.x, wave = tid >> 6, lane = tid & 63;
    const int bm = blockIdx.x * BM, bn = blockIdx.y * 64;
    const int KT = K >> 5;
    const int NT = K >> 5;
    const int NTm = NT - 1;

    floatx4 acc[2][4];
#pragma unroll
    for (int i = 0; i < 2; i++)
#pragma unroll
        for (int j = 0; j < 4; j++) acc[i][j] = (floatx4){0.f, 0.f, 0.f, 0.f};

    const bf16_t* gA0 = A + ((size_t)(bm / 16 + wave * 2 + 0) * KT) * 512 + lane * 8;
    const bf16_t* gA1 = A + ((size_t)(bm / 16 + wave * 2 + 1) * KT) * 512 + lane * 8;
    const bf16_t* gB  = Bt + ((size_t)(bn / 16 + wave) * KT) * 512 + lane * 8;

    auto stageB = [&](int t, int b) {
        gload16(gB + (size_t)t * 512, Bs + b * 2048 + wave * 512);
    };
    auto loadA = [&](bf16x8& r0, bf16x8& r1, int t) {
        const bf16_t* p0 = gA0 + (size_t)t * 512;
        const bf16_t* p1 = gA1 + (size_t)t * 512;
        asm volatile("global_load_dwordx4 %0, %1, off"
                     : "=&v"(r0) : "v"(p0) : "memory");
        asm volatile("global_load_dwordx4 %0, %1, off"
                     : "=&v"(r1) : "v"(p1) : "memory");
    };
    auto computeS = [&](const bf16x8& a0, const bf16x8& a1, int b) {
        bf16x8 bfv[4];
#pragma unroll
        for (int j = 0; j < 4; j++)
            bfv[j] = *(const bf16x8*)&Bs[b * 2048 + j * 512 + lane * 8];
#pragma unroll
        for (int j = 0; j < 4; j++) {
            acc[0][j] = __builtin_amdgcn_mfma_f32_16x16x32_bf16(a0, bfv[j], acc[0][j], 0, 0, 0);
            acc[1][j] = __builtin_amdgcn_mfma_f32_16x16x32_bf16(a1, bfv[j], acc[1][j], 0, 0, 0);
        }
    };

    bf16x8 R[4][2];
#pragma unroll
    for (int i = 0; i < 4; i++) loadA(R[i][0], R[i][1], i);
#pragma unroll
    for (int s = 0; s < 8; s++) stageB(s, s);
    asm volatile("s_waitcnt vmcnt(4)\n\ts_barrier" ::: "memory");

    int bu = 0;
    const int NTI = NT >> 2;
    for (int T = 0; T < NTI; T++) {
        const int t = T << 2;
        if (T) asm volatile("s_waitcnt vmcnt(12)\n\ts_barrier" ::: "memory");
#pragma unroll
        for (int i = 0; i < 4; i++) {
            int bs = bu + 8 + i; if (bs >= D) bs -= D;
            stageB((t + 8 + i) & NTm, bs);
            asm volatile("s_waitcnt vmcnt(10)" ::: "memory");
            __builtin_amdgcn_sched_barrier(0);
            int bc = bu + i; if (bc >= D) bc -= D;
            computeS(R[i][0], R[i][1], bc);
            loadA(R[i][0], R[i][1], (t + 4 + i) & NTm);
        }
        bu += 4; if (bu >= D) bu -= D;
    }
    asm volatile("s_waitcnt vmcnt(0)" ::: "memory");

    const int er = (lane >> 4) * 4, ec = lane & 15;
#pragma unroll
    for (int i = 0; i < 2; i++) {
#pragma unroll
        for (int j = 0; j < 4; j++) {
            const int col = bn + j * 16 + ec;
#pragma unroll
            for (int r = 0; r < 4; r++) {
                const int row = bm + wave * 32 + i * 16 + er + r;
                const size_t idx = (size_t)row * Nout + col;
                outf[idx] = acc[i][j][r] + bias[col] + resid[idx];
            }
        }
    }
}

// ---------------- bf16 MFMA GEMM (QKV, FF1) ------------------------------
// BNt=128 (QKV): 2x2 waves, 4x4 frags, DEPTH=5 (80KB, 2/CU).
// BNt=256 (FF1): 2x2 waves, 4x8 frags, DEPTH=3 (72KB, 2/CU).
template<int EPI, int BNt, int DEPTH>
__global__ __launch_bounds__(256, 2)
void gemm_bt(const bf16_t* __restrict__ A, const bf16_t* __restrict__ Bt,
             const int K,
             const float* __restrict__ bias, const float* __restrict__ resid,
             float* __restrict__ outf, bf16_t* __restrict__ outb,
             bf16_t* __restrict__ aux1, bf16_t* __restrict__ aux2,
             const int Nout)
{
    constexpr int NFRAG = (BNt == 256) ? 8 : 4;    // B-frags per wave
    constexpr int AI    = 4;                       // A-frags per wave
    constexpr int LPS   = (BNt == 256) ? 6 : 4;
    constexpr int BFT   = BNt / 16;                // B ftiles per stage
    constexpr int ASZ = DEPTH * 8 * 512;
    constexpr int BSZ = DEPTH * BFT * 512;
    __shared__ __align__(16) bf16_t smem[ASZ + BSZ];
    bf16_t* Asb = smem;
    bf16_t* Bsb = smem + ASZ;
    const int tid  = threadIdx.x;
    const int wave = tid >> 6, lane = tid & 63;
    const int wr = wave >> 1, wc = wave & 1;  // 2x2 wave grid
    const int bm = blockIdx.x * BM, bn = blockIdx.y * BNt;
    const int KT = K >> 5;

    floatx4 acc[AI][NFRAG];
#pragma unroll
    for (int i = 0; i < AI; i++)
#pragma unroll
        for (int j = 0; j < NFRAG; j++) acc[i][j] = (floatx4){0.f, 0.f, 0.f, 0.f};

    const bf16_t* gA0 = A + ((size_t)(bm / 16 + wave * 2 + 0) * KT) * 512 + lane * 8;
    const bf16_t* gA1 = A + ((size_t)(bm / 16 + wave * 2 + 1) * KT) * 512 + lane * 8;
    const int lA0 = (wave * 2 + 0) * 512;
    const int lA1 = (wave * 2 + 1) * 512;

    const bf16_t* gB[4];
    if (BNt == 256) {
#pragma unroll
        for (int q = 0; q < 4; q++)
            gB[q] = Bt + ((size_t)(bn / 16 + wave * 4 + q) * KT) * 512 + lane * 8;
    } else {
        gB[0] = Bt + ((size_t)(bn / 16 + wave * 2 + 0) * KT) * 512 + lane * 8;
        gB[1] = Bt + ((size_t)(bn / 16 + wave * 2 + 1) * KT) * 512 + lane * 8;
    }

    auto stage = [&](int t, int bu) {
        const size_t off = (size_t)t * 512;
        gload16(gA0 + off, Asb + bu * 4096 + lA0);
        gload16(gA1 + off, Asb + bu * 4096 + lA1);
        if (BNt == 256) {
#pragma unroll
            for (int q = 0; q < 4; q++)
                gload16(gB[q] + off, Bsb + bu * (BFT * 512) + (wave * 4 + q) * 512);
        } else {
            gload16(gB[0] + off, Bsb + bu * 4096 + lA0);
            gload16(gB[1] + off, Bsb + bu * 4096 + lA1);
        }
    };

    auto compute = [&](int bu) {
        bf16x8 af[AI], bfv[NFRAG];
#pragma unroll
        for (int i = 0; i < AI; i++)
            af[i] = *(const bf16x8*)&Asb[bu * 4096 + (wr * 4 + i) * 512 + lane * 8];
#pragma unroll
        for (int j = 0; j < NFRAG; j++)
            bfv[j] = *(const bf16x8*)&Bsb[bu * (BFT * 512) + (wc * NFRAG + j) * 512 + lane * 8];
#pragma unroll
        for (int i = 0; i < AI; i++)
#pragma unroll
            for (int j = 0; j < NFRAG; j++)
                acc[i][j] = __builtin_amdgcn_mfma_f32_16x16x32_bf16(af[i], bfv[j], acc[i][j], 0, 0, 0);
    };

    const int NT = K / BK;
    // ---- every-iter barrier pipeline ----
#pragma unroll
    for (int i = 0; i < DEPTH - 1; ++i) stage(i, i);
    int bu = 0;
    for (int t = 0; t <= NT - DEPTH; ++t) {
        waitvm_barrier<LPS * (DEPTH - 2)>();
        stage(t + DEPTH - 1, bu == 0 ? DEPTH - 1 : bu - 1);
        compute(bu);
        bu = (bu + 1 == DEPTH) ? 0 : bu + 1;
    }
#pragma unroll
    for (int j = DEPTH - 2; j >= 0; --j) {
        waitvm_barrier_rt(LPS * j);
        compute(bu);
        bu = (bu + 1 == DEPTH) ? 0 : bu + 1;
    }

    const int er = (lane >> 4) * 4, ec = lane & 15;
    if constexpr (EPI == 0) {
        if (bn >= 2048) {
            // V-block: LDS transpose then coalesced [d][t] writes
            __syncthreads();                      // staging LDS now dead
            bf16_t* scr = smem;                   // 128 x 136 (pad) bf16 = 34 KB
#pragma unroll
            for (int i = 0; i < AI; i++)
#pragma unroll
                for (int j = 0; j < NFRAG; j++)
#pragma unroll
                    for (int r = 0; r < 4; r++)
                        scr[((wc * NFRAG + j) * 16 + ec) * 136 + (wr * 4 + i) * 16 + er + r] =
                            (bf16_t)acc[i][j][r];
            __syncthreads();
            const int bq = bm >> 10, tmod = bm & 1023, h0 = (bn - 2048) >> 6;
#pragma unroll
            for (int it = 0; it < 8; ++it) {
                const int c = it * 256 + tid;
                const int dl = c >> 4, t16 = c & 15;
                const bf16x8 val = *(const bf16x8*)&scr[dl * 136 + t16 * 8];
                const int h = h0 + (dl >> 6), dd = dl & 63;
                *(bf16x8*)&aux2[(size_t)((bq * 16 + h) * 64 + dd) * 1024 + tmod + t16 * 8] = val;
            }
            return;
        }
    }
#pragma unroll
    for (int i = 0; i < AI; i++) {
#pragma unroll
        for (int j = 0; j < NFRAG; j++) {
            const int col = bn + (wc * NFRAG + j) * 16 + ec;
#pragma unroll
            for (int r = 0; r < 4; r++) {
                const int row = bm + (wr * 4 + i) * 16 + er + r;
                const float v = acc[i][j][r];
                if (EPI == 0) {
                    const int b = row >> 10, t = row & 1023;
                    if (col < 1024) {
                        const int h = col >> 6, d = col & 63;
                        outb[(size_t)((b * 16 + h) * 1024 + t) * 64 + d] = (bf16_t)v;
                    } else {
                        const int c2 = col - 1024, h = c2 >> 6, d = c2 & 63;
                        aux1[(size_t)((b * 16 + h) * 1024 + t) * 64 + d] = (bf16_t)v;
                    }
                } else if (EPI == 2) {
                    outb[ftaddr(row, col, Nout >> 5)] = (bf16_t)fmaxf(v + bias[col], 0.f);
                }
            }
        }
    }
}

// ---------------- flash attention (coalesced swizzled staging) -----------
__global__ __launch_bounds__(256, 4)
void attn_kernel(const bf16_t* __restrict__ Q, const bf16_t* __restrict__ Kg,
                 const bf16_t* __restrict__ Vt, bf16_t* __restrict__ Og)
{
    __shared__ __align__(16) bf16_t Ks[2][4096];
    __shared__ __align__(16) bf16_t Vs[2][4096];
    __shared__ __align__(16) bf16_t Ps[4][1024];
    const int tid = threadIdx.x, wave = tid >> 6, lane = tid & 63;
    const int lin = blockIdx.x + (blockIdx.y << 4);
    const int xcd = lin & 7, idx = lin >> 3;
    const int bh = xcd * 8 + (idx >> 4);
    const int qt = idx & 15;
    const int b = bh >> 4, h = bh & 15;
    const int q0 = qt * 64 + wave * 16;
    const bf16_t* Qb = Q + (size_t)bh * 65536;
    const char* Kb = (const char*)(Kg + (size_t)bh * 65536);
    const char* Vb = (const char*)(Vt + (size_t)bh * 65536);
    const int fr = lane & 15, g = lane >> 4, fk = g * 8;

    const bf16x8 qf0 = *(const bf16x8*)&Qb[(size_t)(q0 + fr) * 64 + fk];
    const bf16x8 qf1 = *(const bf16x8*)&Qb[(size_t)(q0 + fr) * 64 + 32 + fk];

    floatx4 o[4];
#pragma unroll
    for (int dt = 0; dt < 4; dt++) o[dt] = (floatx4){0.f, 0.f, 0.f, 0.f};
    float lsum[4] = {0.f, 0.f, 0.f, 0.f};
    bf16_t* pw = &Ps[wave][0];
    const float sscale = 0.125f * 1.44269504088896f;

    const int sub = lane >> 3;               // row within 8-row group
    const int cc  = (lane & 7) ^ sub;        // swizzled 16B chunk (involution)
    auto stage = [&](int s0, int bu) {
#pragma unroll
        for (int t = 0; t < 2; t++) {
            const int j = wave * 2 + t;      // 8-row slot 0..7
            const int row = j * 8 + sub;     // 0..63
            gload16(Kb + (size_t)(s0 + row) * 128 + cc * 16, &Ks[bu][j * 512]);
            gload16(Vb + (size_t)row * 2048 + (size_t)s0 * 2 + cc * 16, &Vs[bu][j * 512]);
        }
    };

    stage(0, 0);
    int bu = 0;
    for (int it = 0; it < 16; ++it) {
        __syncthreads();
        if (it < 15) stage((it + 1) * 64, bu ^ 1);
        const bf16_t* Kl = Ks[bu];
        const bf16_t* Vl = Vs[bu];

        floatx4 sacc[4];
#pragma unroll
        for (int ss = 0; ss < 4; ss++) sacc[ss] = (floatx4){0.f, 0.f, 0.f, 0.f};
        __builtin_amdgcn_s_setprio(1);
#pragma unroll
        for (int ss = 0; ss < 4; ss++) {
#pragma unroll
            for (int c = 0; c < 2; c++) {
                const int ch = c * 4 + g;
                const bf16x8 qf = (c == 0) ? qf0 : qf1;
                const bf16x8 kf = *(const bf16x8*)
                    &Kl[(ss * 16 + fr) * 64 + ((ch ^ (fr & 7)) << 3)];
                sacc[ss] = __builtin_amdgcn_mfma_f32_16x16x32_bf16(qf, kf, sacc[ss], 0, 0, 0);
            }
        }
        __builtin_amdgcn_s_setprio(0);
#pragma unroll
        for (int ss = 0; ss < 2; ss++) {
#pragma unroll
            for (int r = 0; r < 4; r++) {
                const float p = __builtin_amdgcn_exp2f(sacc[ss][r] * sscale);
                lsum[r] += p;
                const int q = g * 4 + r;
                pw[(ss * 2 + (fr >> 3)) * 128 + q * 8 + (fr & 7)] = (bf16_t)p;
            }
        }
        asm volatile("s_waitcnt lgkmcnt(0)" ::: "memory");
#pragma unroll
        for (int ss = 2; ss < 4; ss++) {
#pragma unroll
            for (int r = 0; r < 4; r++) {
                const float p = __builtin_amdgcn_exp2f(sacc[ss][r] * sscale);
                lsum[r] += p;
                const int q = g * 4 + r;
                pw[(ss * 2 + (fr >> 3)) * 128 + q * 8 + (fr & 7)] = (bf16_t)p;
            }
        }
        {
            const int ch = g;
            const bf16x8 pf = *(const bf16x8*)&pw[ch * 128 + fr * 8];
            __builtin_amdgcn_s_setprio(1);
#pragma unroll
            for (int dt = 0; dt < 4; dt++) {
                const bf16x8 vf = *(const bf16x8*)
                    &Vl[(dt * 16 + fr) * 64 + ((ch ^ (fr & 7)) << 3)];
                o[dt] = __builtin_amdgcn_mfma_f32_16x16x32_bf16(pf, vf, o[dt], 0, 0, 0);
            }
            __builtin_amdgcn_s_setprio(0);
        }
        asm volatile("s_waitcnt lgkmcnt(0)" ::: "memory");
        {
            const int ch = 4 + g;
            const bf16x8 pf = *(const bf16x8*)&pw[ch * 128 + fr * 8];
            __builtin_amdgcn_s_setprio(1);
#pragma unroll
            for (int dt = 0; dt < 4; dt++) {
                const bf16x8 vf = *(const bf16x8*)
                    &Vl[(dt * 16 + fr) * 64 + ((ch ^ (fr & 7)) << 3)];
                o[dt] = __builtin_amdgcn_mfma_f32_16x16x32_bf16(pf, vf, o[dt], 0, 0, 0);
            }
            __builtin_amdgcn_s_setprio(0);
        }
        asm volatile("" ::: "memory");
        bu ^= 1;
    }
#pragma unroll
    for (int r = 0; r < 4; r++) {
        float l = lsum[r];
        l += __shfl_xor(l, 1);
        l += __shfl_xor(l, 2);
        l += __shfl_xor(l, 4);
        l += __shfl_xor(l, 8);
        lsum[r] = 1.0f / l;
    }
    const int tq = q0 + g * 4;
#pragma unroll
    for (int dt = 0; dt < 4; dt++) {
#pragma unroll
        for (int r = 0; r < 4; r++) {
            const int m = b * 1024 + tq + r;
            const int k = h * 64 + dt * 16 + fr;
            Og[ftaddr(m, k, 32)] = (bf16_t)(o[dt][r] * lsum[r]);
        }
    }
}

// -------------------------------------------------------------------------
extern "C" void kernel_launch(void* const* d_in, const int* in_sizes, int n_in,
                              void* d_out, int out_size, void* d_ws, size_t ws_size,
                              hipStream_t stream)
{
    const float* x      = (const float*)d_in[0];
    const float* wq     = (const float*)d_in[1];
    const float* wk     = (const float*)d_in[2];
    const float* wv     = (const float*)d_in[3];
    const float* w_proj = (const float*)d_in[4];
    const float* b_proj = (const float*)d_in[5];
    const float* w1     = (const float*)d_in[6];
    const float* b1     = (const float*)d_in[7];
    const float* w2     = (const float*)d_in[8];
    const float* b2     = (const float*)d_in[9];
    const float* g1     = (const float*)d_in[10];
    const float* be1    = (const float*)d_in[11];
    const float* g2     = (const float*)d_in[12];
    const float* be2    = (const float*)d_in[13];
    float* out = (float*)d_out;
    char* ws = (char*)d_ws;

    bf16_t* WQKVT = (bf16_t*)(ws + 0x0000000);  // [3072,1024] tiled, 6 MB
    bf16_t* WPROJT= (bf16_t*)(ws + 0x0600000);  // [1024,1024] tiled, 2 MB
    bf16_t* W1T   = (bf16_t*)(ws + 0x0800000);  // [4096,1024] tiled, 8 MB
    bf16_t* W2T   = (bf16_t*)(ws + 0x1000000);  // [1024,4096] tiled, 8 MB
    bf16_t* HB    = (bf16_t*)(ws + 0x1800000);  // ln1 out tiled, 8 MB
    bf16_t* Qb    = (bf16_t*)(ws + 0x2000000);  // [BH,T,64] bf16, 8 MB
    bf16_t* Kb    = (bf16_t*)(ws + 0x2800000);  // [BH,T,64] bf16, 8 MB
    bf16_t* Vtb   = (bf16_t*)(ws + 0x3000000);  // [BH,64,T] bf16, 8 MB
    bf16_t* AO    = (bf16_t*)(ws + 0x3800000);  // attn out tiled, 8 MB
    float*  X2    = (float*)(ws + 0x4000000);   // x+sa fp32 row-major, 16 MB
    bf16_t* TB    = (bf16_t*)(ws + 0x2800000);  // ln2(ln2) tiled (reuses Kb), 8 MB
    bf16_t* FF1B  = (bf16_t*)(ws + 0x5000000);  // [4096,4096] tiled, 32 MB

    dim3 blk(256);
    prep_kernel<<<3328, blk, 0, stream>>>(wq, wk, wv, w_proj, w1, w2,
                                          WQKVT, WPROJT, W1T, W2T,
                                          x, g1, be1, HB);
    gemm_bt<0, 128, 5><<<dim3(32, 24), blk, 0, stream>>>(HB, WQKVT, 1024, nullptr, nullptr,
                                                         nullptr, Qb, Kb, Vtb, 3072);
    attn_kernel<<<dim3(16, 64), blk, 0, stream>>>(Qb, Kb, Vtb, AO);
    // proj: reg-A GEMM
    gemm_ra<1><<<dim3(32, 16), blk, 0, stream>>>(AO, WPROJT, 1024, b_proj, x, X2, 1024);
    ln2x_kernel<<<256, blk, 0, stream>>>(X2, g2, be2, TB);
    // FF1: gemm_bt 256-tile
    gemm_bt<2, 256, 3><<<dim3(32, 16), blk, 0, stream>>>(TB, W1T, 1024, b1, nullptr,
                                                         nullptr, FF1B, nullptr, nullptr, 4096);
    // FF2: reg-A GEMM
    gemm_ra<3><<<dim3(32, 16), blk, 0, stream>>>(FF1B, W2T, 4096, b2, X2, out, 1024);
}

// Round 13
// 284.954 us; speedup vs baseline: 1.0634x; 1.0084x over previous
//
#include <hip/hip_runtime.h>
#include <hip/hip_bf16.h>
#include <math.h>
#include <stdint.h>

typedef __bf16 bf16_t;
typedef __bf16 bf16x4 __attribute__((ext_vector_type(4)));
typedef __bf16 bf16x8 __attribute__((ext_vector_type(8)));
typedef float floatx4 __attribute__((ext_vector_type(4)));

#define BM 128
#define BK 32

// fragment-tiled address: 16-row x 32-k tiles, chunk-major inside
__device__ __forceinline__ size_t ftaddr(int m, int k, int KT) {
    return ((size_t)(m >> 4) * KT + (k >> 5)) * 512
         + (((k >> 3) & 3) * 16 + (m & 15)) * 8 + (k & 7);
}

__device__ __forceinline__ void gload16(const void* g, void* lds) {
    __builtin_amdgcn_global_load_lds(
        (__attribute__((address_space(1))) void*)(uintptr_t)g,
        (__attribute__((address_space(3))) void*)(uintptr_t)lds,
        16, 0, 0);
}

// compile-time vmcnt wait + barrier
template<int N>
__device__ __forceinline__ void waitvm_barrier() {
    if constexpr (N == 0)       asm volatile("s_waitcnt vmcnt(0)\n\ts_barrier" ::: "memory");
    else if constexpr (N == 4)  asm volatile("s_waitcnt vmcnt(4)\n\ts_barrier" ::: "memory");
    else if constexpr (N == 6)  asm volatile("s_waitcnt vmcnt(6)\n\ts_barrier" ::: "memory");
    else if constexpr (N == 8)  asm volatile("s_waitcnt vmcnt(8)\n\ts_barrier" ::: "memory");
    else if constexpr (N == 12) asm volatile("s_waitcnt vmcnt(12)\n\ts_barrier" ::: "memory");
    else if constexpr (N == 16) asm volatile("s_waitcnt vmcnt(16)\n\ts_barrier" ::: "memory");
    else static_assert(N == 0, "unsupported vmcnt");
}

// runtime (wave-uniform) vmcnt wait + barrier for the drain tail
__device__ __forceinline__ void waitvm_barrier_rt(int n) {
    switch (n) {
    case 12: asm volatile("s_waitcnt vmcnt(12)\n\ts_barrier" ::: "memory"); break;
    case 8:  asm volatile("s_waitcnt vmcnt(8)\n\ts_barrier"  ::: "memory"); break;
    case 6:  asm volatile("s_waitcnt vmcnt(6)\n\ts_barrier"  ::: "memory"); break;
    case 4:  asm volatile("s_waitcnt vmcnt(4)\n\ts_barrier"  ::: "memory"); break;
    default: asm volatile("s_waitcnt vmcnt(0)\n\ts_barrier"  ::: "memory"); break;
    }
}

// ---------------- prep: weight transposes (blocks 0..3071) + ln1 (3072..3327)
__global__ void prep_kernel(const float* __restrict__ wq, const float* __restrict__ wk,
                            const float* __restrict__ wv, const float* __restrict__ w_proj,
                            const float* __restrict__ w1, const float* __restrict__ w2,
                            bf16_t* __restrict__ WQKVT, bf16_t* __restrict__ WPROJT,
                            bf16_t* __restrict__ W1T, bf16_t* __restrict__ W2T,
                            const float* __restrict__ x, const float* __restrict__ g1,
                            const float* __restrict__ be1, bf16_t* __restrict__ HB)
{
    __shared__ __align__(16) char psm[33024];
    const int tid = threadIdx.x;
    if (blockIdx.x < 3072) {
        // ---- weight transpose + cast, fragment-tiled coalesced writes ----
        float (*tile)[65] = (float(*)[65])psm;
        const int idx = blockIdx.x;
        const float* in; bf16_t* out; int R, C, rt, ct; long nrow0;
        if (idx < 768) {
            const int z = idx >> 8;
            const int hd = (idx >> 4) & 15;
            rt = idx & 15; ct = 0; R = 1024; C = 64;
            in  = (z == 0 ? wq : z == 1 ? wk : wv) + hd * 65536;
            out = WQKVT; nrow0 = z * 1024 + hd * 64;
        } else if (idx < 1024) {
            const int t = idx - 768; rt = t & 15; ct = t >> 4; R = 1024; C = 1024;
            in = w_proj; out = WPROJT; nrow0 = 0;
        } else if (idx < 2048) {
            const int t = idx - 1024; rt = t & 15; ct = t >> 4; R = 1024; C = 4096;
            in = w1; out = W1T; nrow0 = 0;
        } else {
            const int t = idx - 2048; rt = t & 63; ct = t >> 6; R = 4096; C = 1024;
            in = w2; out = W2T; nrow0 = 0;
        }
        const int r0 = rt * 64, c0 = ct * 64;
        const int tr = tid >> 4;
        const int tc = (tid & 15) * 4;
#pragma unroll
        for (int rr = 0; rr < 4; rr++) {
            const int r = tr + rr * 16;
            const float4 v = *(const float4*)&in[(long)(r0 + r) * C + c0 + tc];
            tile[r][tc + 0] = v.x; tile[r][tc + 1] = v.y;
            tile[r][tc + 2] = v.z; tile[r][tc + 3] = v.w;
        }
        __syncthreads();
        const int KT = R >> 5;
        const int w = tid >> 6, l = tid & 63;
        const int c = l >> 4, rr2 = l & 15;
#pragma unroll
        for (int it = 0; it < 2; ++it) {
            const int t8 = it * 4 + w;
            const int kt = t8 >> 2;
            const int nb = t8 & 3;
            const long n = nrow0 + c0 + nb * 16 + rr2;
            const int k = r0 + kt * 32 + c * 8;
            bf16x8 o;
#pragma unroll
            for (int e = 0; e < 8; e++)
                o[e] = (bf16_t)tile[kt * 32 + c * 8 + e][nb * 16 + rr2];
            *(bf16x8*)&out[ftaddr((int)n, k, KT)] = o;
        }
    } else {
        // ---- layernorm, 16 rows/block, tiled-coalesced bf16 out ----
        bf16_t (*ybuf)[1032] = (bf16_t(*)[1032])psm;
        const int wave = tid >> 6, lane = tid & 63;
        const int rb = blockIdx.x - 3072;
        float4 gvv[4], bvv[4];
#pragma unroll
        for (int j = 0; j < 4; j++) {
            gvv[j] = ((const float4*)g1)[lane + j * 64];
            bvv[j] = ((const float4*)be1)[lane + j * 64];
        }
#pragma unroll
        for (int rr = 0; rr < 4; ++rr) {
            const int lrow = wave * 4 + rr;
            const float* xr = x + (size_t)(rb * 16 + lrow) * 1024;
            float4 v[4];
            float s = 0.f, s2 = 0.f;
#pragma unroll
            for (int j = 0; j < 4; j++) {
                v[j] = ((const float4*)xr)[lane + j * 64];
                s  += v[j].x + v[j].y + v[j].z + v[j].w;
                s2 += v[j].x * v[j].x + v[j].y * v[j].y + v[j].z * v[j].z + v[j].w * v[j].w;
            }
#pragma unroll
            for (int off = 32; off >= 1; off >>= 1) {
                s  += __shfl_xor(s, off);
                s2 += __shfl_xor(s2, off);
            }
            const float mu = s * (1.0f / 1024.0f);
            const float rs = rsqrtf(fmaxf(s2 * (1.0f / 1024.0f) - mu * mu, 0.f) + 1e-5f);
#pragma unroll
            for (int j = 0; j < 4; j++) {
                bf16x4 o;
                o[0] = (bf16_t)((v[j].x - mu) * rs * gvv[j].x + bvv[j].x);
                o[1] = (bf16_t)((v[j].y - mu) * rs * gvv[j].y + bvv[j].y);
                o[2] = (bf16_t)((v[j].z - mu) * rs * gvv[j].z + bvv[j].z);
                o[3] = (bf16_t)((v[j].w - mu) * rs * gvv[j].w + bvv[j].w);
                *(bf16x4*)&ybuf[lrow][(lane + j * 64) * 4] = o;
            }
        }
        __syncthreads();
        bf16_t* outBase = HB + (size_t)rb * 32 * 512;
#pragma unroll
        for (int it = 0; it < 8; ++it) {
            const int s = it * 256 + tid;
            const int kt = s >> 6, c = (s >> 4) & 3, rr2 = s & 15;
            const bf16x8 val = *(const bf16x8*)&ybuf[rr2][kt * 32 + c * 8];
            *(bf16x8*)&outBase[(size_t)s * 8] = val;
        }
    }
}

// ---------------- double layernorm: ln(ln(x)), tiled-coalesced out ------
__global__ void ln2x_kernel(const float* __restrict__ x, const float* __restrict__ g,
                            const float* __restrict__ b, bf16_t* __restrict__ outb)
{
    __shared__ __align__(16) bf16_t ybuf[16][1032];
    const int tid = threadIdx.x, wave = tid >> 6, lane = tid & 63;
    const int rb = blockIdx.x;
    float4 gvv[4], bvv[4];
#pragma unroll
    for (int j = 0; j < 4; j++) {
        gvv[j] = ((const float4*)g)[lane + j * 64];
        bvv[j] = ((const float4*)b)[lane + j * 64];
    }
#pragma unroll
    for (int rr = 0; rr < 4; ++rr) {
        const int lrow = wave * 4 + rr;
        const float* xr = x + (size_t)(rb * 16 + lrow) * 1024;
        float4 v[4];
        float s = 0.f, s2 = 0.f;
#pragma unroll
        for (int j = 0; j < 4; j++) {
            v[j] = ((const float4*)xr)[lane + j * 64];
            s  += v[j].x + v[j].y + v[j].z + v[j].w;
            s2 += v[j].x * v[j].x + v[j].y * v[j].y + v[j].z * v[j].z + v[j].w * v[j].w;
        }
#pragma unroll
        for (int off = 32; off >= 1; off >>= 1) {
            s  += __shfl_xor(s, off);
            s2 += __shfl_xor(s2, off);
        }
        float mu = s * (1.0f / 1024.0f);
        float rs = rsqrtf(fmaxf(s2 * (1.0f / 1024.0f) - mu * mu, 0.f) + 1e-5f);
        s = 0.f; s2 = 0.f;
#pragma unroll
        for (int j = 0; j < 4; j++) {
            v[j].x = (v[j].x - mu) * rs * gvv[j].x + bvv[j].x;
            v[j].y = (v[j].y - mu) * rs * gvv[j].y + bvv[j].y;
            v[j].z = (v[j].z - mu) * rs * gvv[j].z + bvv[j].z;
            v[j].w = (v[j].w - mu) * rs * gvv[j].w + bvv[j].w;
            s  += v[j].x + v[j].y + v[j].z + v[j].w;
            s2 += v[j].x * v[j].x + v[j].y * v[j].y + v[j].z * v[j].z + v[j].w * v[j].w;
        }
#pragma unroll
        for (int off = 32; off >= 1; off >>= 1) {
            s  += __shfl_xor(s, off);
            s2 += __shfl_xor(s2, off);
        }
        mu = s * (1.0f / 1024.0f);
        rs = rsqrtf(fmaxf(s2 * (1.0f / 1024.0f) - mu * mu, 0.f) + 1e-5f);
#pragma unroll
        for (int j = 0; j < 4; j++) {
            bf16x4 o;
            o[0] = (bf16_t)((v[j].x - mu) * rs * gvv[j].x + bvv[j].x);
            o[1] = (bf16_t)((v[j].y - mu) * rs * gvv[j].y + bvv[j].y);
            o[2] = (bf16_t)((v[j].z - mu) * rs * gvv[j].z + bvv[j].z);
            o[3] = (bf16_t)((v[j].w - mu) * rs * gvv[j].w + bvv[j].w);
            *(bf16x4*)&ybuf[lrow][(lane + j * 64) * 4] = o;
        }
    }
    __syncthreads();
    bf16_t* outBase = outb + (size_t)rb * 32 * 512;
#pragma unroll
    for (int it = 0; it < 8; ++it) {
        const int s = it * 256 + tid;
        const int kt = s >> 6, c = (s >> 4) & 3, rr2 = s & 15;
        const bf16x8 val = *(const bf16x8*)&ybuf[rr2][kt * 32 + c * 8];
        *(bf16x8*)&outBase[(size_t)s * 8] = val;
    }
}

// ---------------- reg-A GEMM (proj, FF2): 128x64 tile, B-only LDS --------
// DEEP=4 schedule, verified R8/R9/R12. R11 probe: deeper A-prefetch NULL.
template<int EPI>
__global__ __launch_bounds__(256, 2)
void gemm_ra(const bf16_t* __restrict__ A, const bf16_t* __restrict__ Bt,
             const int K, const float* __restrict__ bias,
             const float* __restrict__ resid, float* __restrict__ outf,
             const int Nout)
{
    constexpr int D = 12;
    __shared__ __align__(16) bf16_t Bs[D * 2048];   // 48 KB
    const int tid = threadIdx.x, wave = tid >> 6, lane = tid & 63;
    const int bm = blockIdx.x * BM, bn = blockIdx.y * 64;
    const int KT = K >> 5;
    const int NT = K >> 5;
    const int NTm = NT - 1;

    floatx4 acc[2][4];
#pragma unroll
    for (int i = 0; i < 2; i++)
#pragma unroll
        for (int j = 0; j < 4; j++) acc[i][j] = (floatx4){0.f, 0.f, 0.f, 0.f};

    const bf16_t* gA0 = A + ((size_t)(bm / 16 + wave * 2 + 0) * KT) * 512 + lane * 8;
    const bf16_t* gA1 = A + ((size_t)(bm / 16 + wave * 2 + 1) * KT) * 512 + lane * 8;
    const bf16_t* gB  = Bt + ((size_t)(bn / 16 + wave) * KT) * 512 + lane * 8;

    auto stageB = [&](int t, int b) {
        gload16(gB + (size_t)t * 512, Bs + b * 2048 + wave * 512);
    };
    auto loadA = [&](bf16x8& r0, bf16x8& r1, int t) {
        const bf16_t* p0 = gA0 + (size_t)t * 512;
        const bf16_t* p1 = gA1 + (size_t)t * 512;
        asm volatile("global_load_dwordx4 %0, %1, off"
                     : "=&v"(r0) : "v"(p0) : "memory");
        asm volatile("global_load_dwordx4 %0, %1, off"
                     : "=&v"(r1) : "v"(p1) : "memory");
    };
    auto computeS = [&](const bf16x8& a0, const bf16x8& a1, int b) {
        bf16x8 bfv[4];
#pragma unroll
        for (int j = 0; j < 4; j++)
            bfv[j] = *(const bf16x8*)&Bs[b * 2048 + j * 512 + lane * 8];
#pragma unroll
        for (int j = 0; j < 4; j++) {
            acc[0][j] = __builtin_amdgcn_mfma_f32_16x16x32_bf16(a0, bfv[j], acc[0][j], 0, 0, 0);
            acc[1][j] = __builtin_amdgcn_mfma_f32_16x16x32_bf16(a1, bfv[j], acc[1][j], 0, 0, 0);
        }
    };

    bf16x8 R[4][2];
#pragma unroll
    for (int i = 0; i < 4; i++) loadA(R[i][0], R[i][1], i);
#pragma unroll
    for (int s = 0; s < 8; s++) stageB(s, s);
    asm volatile("s_waitcnt vmcnt(4)\n\ts_barrier" ::: "memory");

    int bu = 0;
    const int NTI = NT >> 2;
    for (int T = 0; T < NTI; T++) {
        const int t = T << 2;
        if (T) asm volatile("s_waitcnt vmcnt(12)\n\ts_barrier" ::: "memory");
#pragma unroll
        for (int i = 0; i < 4; i++) {
            int bs = bu + 8 + i; if (bs >= D) bs -= D;
            stageB((t + 8 + i) & NTm, bs);
            asm volatile("s_waitcnt vmcnt(10)" ::: "memory");
            __builtin_amdgcn_sched_barrier(0);
            int bc = bu + i; if (bc >= D) bc -= D;
            computeS(R[i][0], R[i][1], bc);
            loadA(R[i][0], R[i][1], (t + 4 + i) & NTm);
        }
        bu += 4; if (bu >= D) bu -= D;
    }
    asm volatile("s_waitcnt vmcnt(0)" ::: "memory");

    const int er = (lane >> 4) * 4, ec = lane & 15;
#pragma unroll
    for (int i = 0; i < 2; i++) {
#pragma unroll
        for (int j = 0; j < 4; j++) {
            const int col = bn + j * 16 + ec;
#pragma unroll
            for (int r = 0; r < 4; r++) {
                const int row = bm + wave * 32 + i * 16 + er + r;
                const size_t idx = (size_t)row * Nout + col;
                outf[idx] = acc[i][j][r] + bias[col] + resid[idx];
            }
        }
    }
}

// ---------------- bf16 MFMA GEMM (QKV, FF1) ------------------------------
// BNt=128 (QKV): 2x2 waves, 4x4 frags. R13: DEPTH=3 (48KB -> 3 blocks/CU)
//   so grid 768 = 256x3 runs in ONE full-residency round (DEPTH=5's 80KB
//   allowed only 2/CU -> 512+256 tail = 1.5 rounds).
// BNt=256 (FF1): 2x2 waves, 4x8 frags, DEPTH=3 (72KB, 2/CU).
template<int EPI, int BNt, int DEPTH>
__global__ __launch_bounds__(256, 2)
void gemm_bt(const bf16_t* __restrict__ A, const bf16_t* __restrict__ Bt,
             const int K,
             const float* __restrict__ bias, const float* __restrict__ resid,
             float* __restrict__ outf, bf16_t* __restrict__ outb,
             bf16_t* __restrict__ aux1, bf16_t* __restrict__ aux2,
             const int Nout)
{
    constexpr int NFRAG = (BNt == 256) ? 8 : 4;    // B-frags per wave
    constexpr int AI    = 4;                       // A-frags per wave
    constexpr int LPS   = (BNt == 256) ? 6 : 4;
    constexpr int BFT   = BNt / 16;                // B ftiles per stage
    constexpr int ASZ = DEPTH * 8 * 512;
    constexpr int BSZ = DEPTH * BFT * 512;
    __shared__ __align__(16) bf16_t smem[ASZ + BSZ];
    bf16_t* Asb = smem;
    bf16_t* Bsb = smem + ASZ;
    const int tid  = threadIdx.x;
    const int wave = tid >> 6, lane = tid & 63;
    const int wr = wave >> 1, wc = wave & 1;  // 2x2 wave grid
    const int bm = blockIdx.x * BM, bn = blockIdx.y * BNt;
    const int KT = K >> 5;

    floatx4 acc[AI][NFRAG];
#pragma unroll
    for (int i = 0; i < AI; i++)
#pragma unroll
        for (int j = 0; j < NFRAG; j++) acc[i][j] = (floatx4){0.f, 0.f, 0.f, 0.f};

    const bf16_t* gA0 = A + ((size_t)(bm / 16 + wave * 2 + 0) * KT) * 512 + lane * 8;
    const bf16_t* gA1 = A + ((size_t)(bm / 16 + wave * 2 + 1) * KT) * 512 + lane * 8;
    const int lA0 = (wave * 2 + 0) * 512;
    const int lA1 = (wave * 2 + 1) * 512;

    const bf16_t* gB[4];
    if (BNt == 256) {
#pragma unroll
        for (int q = 0; q < 4; q++)
            gB[q] = Bt + ((size_t)(bn / 16 + wave * 4 + q) * KT) * 512 + lane * 8;
    } else {
        gB[0] = Bt + ((size_t)(bn / 16 + wave * 2 + 0) * KT) * 512 + lane * 8;
        gB[1] = Bt + ((size_t)(bn / 16 + wave * 2 + 1) * KT) * 512 + lane * 8;
    }

    auto stage = [&](int t, int bu) {
        const size_t off = (size_t)t * 512;
        gload16(gA0 + off, Asb + bu * 4096 + lA0);
        gload16(gA1 + off, Asb + bu * 4096 + lA1);
        if (BNt == 256) {
#pragma unroll
            for (int q = 0; q < 4; q++)
                gload16(gB[q] + off, Bsb + bu * (BFT * 512) + (wave * 4 + q) * 512);
        } else {
            gload16(gB[0] + off, Bsb + bu * 4096 + lA0);
            gload16(gB[1] + off, Bsb + bu * 4096 + lA1);
        }
    };

    auto compute = [&](int bu) {
        bf16x8 af[AI], bfv[NFRAG];
#pragma unroll
        for (int i = 0; i < AI; i++)
            af[i] = *(const bf16x8*)&Asb[bu * 4096 + (wr * 4 + i) * 512 + lane * 8];
#pragma unroll
        for (int j = 0; j < NFRAG; j++)
            bfv[j] = *(const bf16x8*)&Bsb[bu * (BFT * 512) + (wc * NFRAG + j) * 512 + lane * 8];
#pragma unroll
        for (int i = 0; i < AI; i++)
#pragma unroll
            for (int j = 0; j < NFRAG; j++)
                acc[i][j] = __builtin_amdgcn_mfma_f32_16x16x32_bf16(af[i], bfv[j], acc[i][j], 0, 0, 0);
    };

    const int NT = K / BK;
    // ---- every-iter barrier pipeline ----
#pragma unroll
    for (int i = 0; i < DEPTH - 1; ++i) stage(i, i);
    int bu = 0;
    for (int t = 0; t <= NT - DEPTH; ++t) {
        waitvm_barrier<LPS * (DEPTH - 2)>();
        stage(t + DEPTH - 1, bu == 0 ? DEPTH - 1 : bu - 1);
        compute(bu);
        bu = (bu + 1 == DEPTH) ? 0 : bu + 1;
    }
#pragma unroll
    for (int j = DEPTH - 2; j >= 0; --j) {
        waitvm_barrier_rt(LPS * j);
        compute(bu);
        bu = (bu + 1 == DEPTH) ? 0 : bu + 1;
    }

    const int er = (lane >> 4) * 4, ec = lane & 15;
    if constexpr (EPI == 0) {
        if (bn >= 2048) {
            // V-block: LDS transpose then coalesced [d][t] writes
            __syncthreads();                      // staging LDS now dead
            bf16_t* scr = smem;                   // 128 x 136 (pad) bf16 = 34 KB
#pragma unroll
            for (int i = 0; i < AI; i++)
#pragma unroll
                for (int j = 0; j < NFRAG; j++)
#pragma unroll
                    for (int r = 0; r < 4; r++)
                        scr[((wc * NFRAG + j) * 16 + ec) * 136 + (wr * 4 + i) * 16 + er + r] =
                            (bf16_t)acc[i][j][r];
            __syncthreads();
            const int bq = bm >> 10, tmod = bm & 1023, h0 = (bn - 2048) >> 6;
#pragma unroll
            for (int it = 0; it < 8; ++it) {
                const int c = it * 256 + tid;
                const int dl = c >> 4, t16 = c & 15;
                const bf16x8 val = *(const bf16x8*)&scr[dl * 136 + t16 * 8];
                const int h = h0 + (dl >> 6), dd = dl & 63;
                *(bf16x8*)&aux2[(size_t)((bq * 16 + h) * 64 + dd) * 1024 + tmod + t16 * 8] = val;
            }
            return;
        }
    }
#pragma unroll
    for (int i = 0; i < AI; i++) {
#pragma unroll
        for (int j = 0; j < NFRAG; j++) {
            const int col = bn + (wc * NFRAG + j) * 16 + ec;
#pragma unroll
            for (int r = 0; r < 4; r++) {
                const int row = bm + (wr * 4 + i) * 16 + er + r;
                const float v = acc[i][j][r];
                if (EPI == 0) {
                    const int b = row >> 10, t = row & 1023;
                    if (col < 1024) {
                        const int h = col >> 6, d = col & 63;
                        outb[(size_t)((b * 16 + h) * 1024 + t) * 64 + d] = (bf16_t)v;
                    } else {
                        const int c2 = col - 1024, h = c2 >> 6, d = c2 & 63;
                        aux1[(size_t)((b * 16 + h) * 1024 + t) * 64 + d] = (bf16_t)v;
                    }
                } else if (EPI == 2) {
                    outb[ftaddr(row, col, Nout >> 5)] = (bf16_t)fmaxf(v + bias[col], 0.f);
                }
            }
        }
    }
}

// ---------------- flash attention (coalesced swizzled staging) -----------
__global__ __launch_bounds__(256, 4)
void attn_kernel(const bf16_t* __restrict__ Q, const bf16_t* __restrict__ Kg,
                 const bf16_t* __restrict__ Vt, bf16_t* __restrict__ Og)
{
    __shared__ __align__(16) bf16_t Ks[2][4096];
    __shared__ __align__(16) bf16_t Vs[2][4096];
    __shared__ __align__(16) bf16_t Ps[4][1024];
    const int tid = threadIdx.x, wave = tid >> 6, lane = tid & 63;
    const int lin = blockIdx.x + (blockIdx.y << 4);
    const int xcd = lin & 7, idx = lin >> 3;
    const int bh = xcd * 8 + (idx >> 4);
    const int qt = idx & 15;
    const int b = bh >> 4, h = bh & 15;
    const int q0 = qt * 64 + wave * 16;
    const bf16_t* Qb = Q + (size_t)bh * 65536;
    const char* Kb = (const char*)(Kg + (size_t)bh * 65536);
    const char* Vb = (const char*)(Vt + (size_t)bh * 65536);
    const int fr = lane & 15, g = lane >> 4, fk = g * 8;

    const bf16x8 qf0 = *(const bf16x8*)&Qb[(size_t)(q0 + fr) * 64 + fk];
    const bf16x8 qf1 = *(const bf16x8*)&Qb[(size_t)(q0 + fr) * 64 + 32 + fk];

    floatx4 o[4];
#pragma unroll
    for (int dt = 0; dt < 4; dt++) o[dt] = (floatx4){0.f, 0.f, 0.f, 0.f};
    float lsum[4] = {0.f, 0.f, 0.f, 0.f};
    bf16_t* pw = &Ps[wave][0];
    const float sscale = 0.125f * 1.44269504088896f;

    const int sub = lane >> 3;               // row within 8-row group
    const int cc  = (lane & 7) ^ sub;        // swizzled 16B chunk (involution)
    auto stage = [&](int s0, int bu) {
#pragma unroll
        for (int t = 0; t < 2; t++) {
            const int j = wave * 2 + t;      // 8-row slot 0..7
            const int row = j * 8 + sub;     // 0..63
            gload16(Kb + (size_t)(s0 + row) * 128 + cc * 16, &Ks[bu][j * 512]);
            gload16(Vb + (size_t)row * 2048 + (size_t)s0 * 2 + cc * 16, &Vs[bu][j * 512]);
        }
    };

    stage(0, 0);
    int bu = 0;
    for (int it = 0; it < 16; ++it) {
        __syncthreads();
        if (it < 15) stage((it + 1) * 64, bu ^ 1);
        const bf16_t* Kl = Ks[bu];
        const bf16_t* Vl = Vs[bu];

        floatx4 sacc[4];
#pragma unroll
        for (int ss = 0; ss < 4; ss++) sacc[ss] = (floatx4){0.f, 0.f, 0.f, 0.f};
        __builtin_amdgcn_s_setprio(1);
#pragma unroll
        for (int ss = 0; ss < 4; ss++) {
#pragma unroll
            for (int c = 0; c < 2; c++) {
                const int ch = c * 4 + g;
                const bf16x8 qf = (c == 0) ? qf0 : qf1;
                const bf16x8 kf = *(const bf16x8*)
                    &Kl[(ss * 16 + fr) * 64 + ((ch ^ (fr & 7)) << 3)];
                sacc[ss] = __builtin_amdgcn_mfma_f32_16x16x32_bf16(qf, kf, sacc[ss], 0, 0, 0);
            }
        }
        __builtin_amdgcn_s_setprio(0);
#pragma unroll
        for (int ss = 0; ss < 2; ss++) {
#pragma unroll
            for (int r = 0; r < 4; r++) {
                const float p = __builtin_amdgcn_exp2f(sacc[ss][r] * sscale);
                lsum[r] += p;
                const int q = g * 4 + r;
                pw[(ss * 2 + (fr >> 3)) * 128 + q * 8 + (fr & 7)] = (bf16_t)p;
            }
        }
        asm volatile("s_waitcnt lgkmcnt(0)" ::: "memory");
#pragma unroll
        for (int ss = 2; ss < 4; ss++) {
#pragma unroll
            for (int r = 0; r < 4; r++) {
                const float p = __builtin_amdgcn_exp2f(sacc[ss][r] * sscale);
                lsum[r] += p;
                const int q = g * 4 + r;
                pw[(ss * 2 + (fr >> 3)) * 128 + q * 8 + (fr & 7)] = (bf16_t)p;
            }
        }
        {
            const int ch = g;
            const bf16x8 pf = *(const bf16x8*)&pw[ch * 128 + fr * 8];
            __builtin_amdgcn_s_setprio(1);
#pragma unroll
            for (int dt = 0; dt < 4; dt++) {
                const bf16x8 vf = *(const bf16x8*)
                    &Vl[(dt * 16 + fr) * 64 + ((ch ^ (fr & 7)) << 3)];
                o[dt] = __builtin_amdgcn_mfma_f32_16x16x32_bf16(pf, vf, o[dt], 0, 0, 0);
            }
            __builtin_amdgcn_s_setprio(0);
        }
        asm volatile("s_waitcnt lgkmcnt(0)" ::: "memory");
        {
            const int ch = 4 + g;
            const bf16x8 pf = *(const bf16x8*)&pw[ch * 128 + fr * 8];
            __builtin_amdgcn_s_setprio(1);
#pragma unroll
            for (int dt = 0; dt < 4; dt++) {
                const bf16x8 vf = *(const bf16x8*)
                    &Vl[(dt * 16 + fr) * 64 + ((ch ^ (fr & 7)) << 3)];
                o[dt] = __builtin_amdgcn_mfma_f32_16x16x32_bf16(pf, vf, o[dt], 0, 0, 0);
            }
            __builtin_amdgcn_s_setprio(0);
        }
        asm volatile("" ::: "memory");
        bu ^= 1;
    }
#pragma unroll
    for (int r = 0; r < 4; r++) {
        float l = lsum[r];
        l += __shfl_xor(l, 1);
        l += __shfl_xor(l, 2);
        l += __shfl_xor(l, 4);
        l += __shfl_xor(l, 8);
        lsum[r] = 1.0f / l;
    }
    const int tq = q0 + g * 4;
#pragma unroll
    for (int dt = 0; dt < 4; dt++) {
#pragma unroll
        for (int r = 0; r < 4; r++) {
            const int m = b * 1024 + tq + r;
            const int k = h * 64 + dt * 16 + fr;
            Og[ftaddr(m, k, 32)] = (bf16_t)(o[dt][r] * lsum[r]);
        }
    }
}

// -------------------------------------------------------------------------
extern "C" void kernel_launch(void* const* d_in, const int* in_sizes, int n_in,
                              void* d_out, int out_size, void* d_ws, size_t ws_size,
                              hipStream_t stream)
{
    const float* x      = (const float*)d_in[0];
    const float* wq     = (const float*)d_in[1];
    const float* wk     = (const float*)d_in[2];
    const float* wv     = (const float*)d_in[3];
    const float* w_proj = (const float*)d_in[4];
    const float* b_proj = (const float*)d_in[5];
    const float* w1     = (const float*)d_in[6];
    const float* b1     = (const float*)d_in[7];
    const float* w2     = (const float*)d_in[8];
    const float* b2     = (const float*)d_in[9];
    const float* g1     = (const float*)d_in[10];
    const float* be1    = (const float*)d_in[11];
    const float* g2     = (const float*)d_in[12];
    const float* be2    = (const float*)d_in[13];
    float* out = (float*)d_out;
    char* ws = (char*)d_ws;

    bf16_t* WQKVT = (bf16_t*)(ws + 0x0000000);  // [3072,1024] tiled, 6 MB
    bf16_t* WPROJT= (bf16_t*)(ws + 0x0600000);  // [1024,1024] tiled, 2 MB
    bf16_t* W1T   = (bf16_t*)(ws + 0x0800000);  // [4096,1024] tiled, 8 MB
    bf16_t* W2T   = (bf16_t*)(ws + 0x1000000);  // [1024,4096] tiled, 8 MB
    bf16_t* HB    = (bf16_t*)(ws + 0x1800000);  // ln1 out tiled, 8 MB
    bf16_t* Qb    = (bf16_t*)(ws + 0x2000000);  // [BH,T,64] bf16, 8 MB
    bf16_t* Kb    = (bf16_t*)(ws + 0x2800000);  // [BH,T,64] bf16, 8 MB
    bf16_t* Vtb   = (bf16_t*)(ws + 0x3000000);  // [BH,64,T] bf16, 8 MB
    bf16_t* AO    = (bf16_t*)(ws + 0x3800000);  // attn out tiled, 8 MB
    float*  X2    = (float*)(ws + 0x4000000);   // x+sa fp32 row-major, 16 MB
    bf16_t* TB    = (bf16_t*)(ws + 0x2800000);  // ln2(ln2) tiled (reuses Kb), 8 MB
    bf16_t* FF1B  = (bf16_t*)(ws + 0x5000000);  // [4096,4096] tiled, 32 MB

    dim3 blk(256);
    prep_kernel<<<3328, blk, 0, stream>>>(wq, wk, wv, w_proj, w1, w2,
                                          WQKVT, WPROJT, W1T, W2T,
                                          x, g1, be1, HB);
    // QKV: DEPTH=3 -> 48KB LDS -> 3 blocks/CU -> 768 blocks in ONE round
    gemm_bt<0, 128, 3><<<dim3(32, 24), blk, 0, stream>>>(HB, WQKVT, 1024, nullptr, nullptr,
                                                         nullptr, Qb, Kb, Vtb, 3072);
    attn_kernel<<<dim3(16, 64), blk, 0, stream>>>(Qb, Kb, Vtb, AO);
    // proj: reg-A GEMM
    gemm_ra<1><<<dim3(32, 16), blk, 0, stream>>>(AO, WPROJT, 1024, b_proj, x, X2, 1024);
    ln2x_kernel<<<256, blk, 0, stream>>>(X2, g2, be2, TB);
    // FF1: gemm_bt 256-tile
    gemm_bt<2, 256, 3><<<dim3(32, 16), blk, 0, stream>>>(TB, W1T, 1024, b1, nullptr,
                                                         nullptr, FF1B, nullptr, nullptr, 4096);
    // FF2: reg-A GEMM
    gemm_ra<3><<<dim3(32, 16), blk, 0, stream>>>(FF1B, W2T, 4096, b2, X2, out, 1024);
}